// Round 13
// baseline (1595.189 us; speedup 1.0000x reference)
//
#include <hip/hip_runtime.h>

// Problem dims
constexpr int VOC  = 50005;
constexpr int VOCP2= 50176;   // 196*256, padded vocab
constexpr int NT2  = 196;     // vocab tiles (256)
constexpr int NTMP = 400;     // padded partial stride
constexpr int KSN  = 8784;    // KNOW-1
constexpr float NPAD = 41221.0f;

typedef unsigned short u16;
typedef __attribute__((ext_vector_type(4))) float f32x4;
typedef __attribute__((ext_vector_type(8))) short bf16x8;

__device__ __forceinline__ float dot4(float4 a, float4 b) {
    return a.x*b.x + a.y*b.y + a.z*b.z + a.w*b.w;
}
__device__ __forceinline__ float sigmoidf_(float x) { return 1.0f / (1.0f + expf(-x)); }
__device__ __forceinline__ u16 f2bf(float f) {
    unsigned x = __float_as_uint(f);
    return (u16)((x + 0x7FFFu + ((x >> 16) & 1u)) >> 16);
}
__device__ __forceinline__ float bf2f(u16 u) { return __uint_as_float(((unsigned)u) << 16); }
__device__ __forceinline__ bf16x8 pack8(float4 lo, float4 hi) {
    union { bf16x8 v; unsigned u[4]; } r;
    r.u[0] = f2bf(lo.x) | ((unsigned)f2bf(lo.y) << 16);
    r.u[1] = f2bf(lo.z) | ((unsigned)f2bf(lo.w) << 16);
    r.u[2] = f2bf(hi.x) | ((unsigned)f2bf(hi.y) << 16);
    r.u[3] = f2bf(hi.z) | ((unsigned)f2bf(hi.w) << 16);
    return r.v;
}
template<int AUX>
__device__ __forceinline__ void gload_lds16x(const void* g, void* l) {
    __builtin_amdgcn_global_load_lds((const __attribute__((address_space(1))) unsigned int*)g,
                                     (__attribute__((address_space(3))) unsigned int*)l, 16, 0, AUX);
}
__device__ __forceinline__ void gload_lds16(const void* g, void* l) { gload_lds16x<0>(g, l); }
// device-coherent u16 store (write-through to coherence point, cross-XCD visible)
__device__ __forceinline__ void store_u16_sc(u16* p, u16 v) {
    asm volatile("global_store_short %0, %1, off sc0 sc1" :: "v"(p), "v"((unsigned)v) : "memory");
}

// ---------------------------------------------------------------- cvt fp32 -> bf16 (strided)
__global__ __launch_bounds__(256) void k_cvt(const float* __restrict__ src, u16* __restrict__ dst,
                                             int ncols, int sld, int dld) {
    int row = blockIdx.x;
    int c = (blockIdx.y * 256 + threadIdx.x) * 4;
    if (c >= ncols) return;
    float4 v = *(const float4*)(src + (size_t)row * sld + c);
    unsigned lo = f2bf(v.x) | ((unsigned)f2bf(v.y) << 16);
    unsigned hi = f2bf(v.z) | ((unsigned)f2bf(v.w) << 16);
    *(uint2*)(dst + (size_t)row * dld + c) = make_uint2(lo, hi);
}

// zero pad rows 50005..50175 of A34 and Aemb (both VOCP2)
__global__ __launch_bounds__(256) void k_pad0(u16* __restrict__ Aemb, u16* __restrict__ A34) {
    int r = VOC + blockIdx.x;            // 50005..50175
    unsigned* p3 = (unsigned*)(A34 + (size_t)r * 1536);
    for (int i = threadIdx.x; i < 768; i += 256) p3[i] = 0;
    unsigned* pe = (unsigned*)(Aemb + (size_t)r * 512);
    if (threadIdx.x < 256) pe[threadIdx.x] = 0;
}

// build Bsk [128][2048] bf16: rows 0..31 = [ses|know], rows 32..127 = 0
__global__ __launch_bounds__(256) void k_bsk(const float* __restrict__ ses,
                                             const float* __restrict__ know,
                                             u16* __restrict__ Bsk) {
    int row = blockIdx.x;
    for (int c0 = threadIdx.x * 4; c0 < 2048; c0 += 1024) {
        uint2 val = make_uint2(0, 0);
        if (row < 32) {
            const float* srcp = (c0 < 1024) ? ses + (size_t)row * 1024 + c0
                                            : know + (size_t)row * 1024 + (c0 - 1024);
            float4 v = *(const float4*)srcp;
            val = make_uint2(f2bf(v.x) | ((unsigned)f2bf(v.y) << 16),
                             f2bf(v.z) | ((unsigned)f2bf(v.w) << 16));
        }
        *(uint2*)(Bsk + (size_t)row * 2048 + c0) = val;
    }
}

// ---------------------------------------------------------------- gather target embeddings -> BG[:,1024:1536] bf16
__global__ __launch_bounds__(128) void k_gather(const float* __restrict__ embed,
                                                const int* __restrict__ target,
                                                u16* __restrict__ BG) {
    int n = blockIdx.x;
    int row = target[n];
    int c = threadIdx.x * 4;
    float4 v = *(const float4*)(embed + (size_t)row * 512 + c);
    unsigned lo = f2bf(v.x) | ((unsigned)f2bf(v.y) << 16);
    unsigned hi = f2bf(v.z) | ((unsigned)f2bf(v.w) << 16);
    *(uint2*)(BG + (size_t)n * 1536 + 1024 + c) = make_uint2(lo, hi);
}

// ------------------------------------------------- h0 + ses_inf_vec (fp32, small)
__global__ __launch_bounds__(256) void k_h0_sesinf(const float* __restrict__ ses,
                                                   const float* __restrict__ sdw,
                                                   const float* __restrict__ sdb,
                                                   const float* __restrict__ siw,
                                                   float* __restrict__ h0,
                                                   float* __restrict__ sesinf) {
    int g = blockIdx.x * 256 + threadIdx.x;
    int b = g & 31;
    int jg = g >> 5;
    int j0 = jg * 4;
    const float4* s4 = (const float4*)(ses + (size_t)b * 1024);
    const float4* wa[4];
    const float4* wc[4];
#pragma unroll
    for (int r = 0; r < 4; ++r) {
        wa[r] = (const float4*)(sdw + (size_t)(j0 + r) * 1024);
        wc[r] = (const float4*)(siw + (size_t)(j0 + r) * 1024);
    }
    float a[4] = {0, 0, 0, 0}, c[4] = {0, 0, 0, 0};
    for (int kq = 0; kq < 256; ++kq) {
        float4 sv = s4[kq];
#pragma unroll
        for (int r = 0; r < 4; ++r) { a[r] += dot4(sv, wa[r][kq]); c[r] += dot4(sv, wc[r][kq]); }
    }
#pragma unroll
    for (int r = 0; r < 4; ++r) {
        h0[b * 1024 + j0 + r] = tanhf(a[r] + sdb[j0 + r]);
        sesinf[b * 1024 + j0 + r] = c[r];
    }
}

// ------------------------------------------------- lse of padded know scores
__global__ __launch_bounds__(256) void k_lseknow(const float* __restrict__ ks,
                                                 float* __restrict__ lsek) {
    int b = blockIdx.x;
    int t = threadIdx.x;
    __shared__ float sm[256];
    float m = -1e30f;
    for (int j = t; j < KSN; j += 256) m = fmaxf(m, ks[(size_t)b * KSN + j]);
    sm[t] = m;
    __syncthreads();
    for (int s = 128; s > 0; s >>= 1) { if (t < s) sm[t] = fmaxf(sm[t], sm[t + s]); __syncthreads(); }
    m = fmaxf(sm[0], 0.0f);
    __syncthreads();
    float s = 0.0f;
    for (int j = t; j < KSN; j += 256) s += expf(ks[(size_t)b * KSN + j] - m);
    sm[t] = s;
    __syncthreads();
    for (int r = 128; r > 0; r >>= 1) { if (t < r) sm[t] += sm[t + r]; __syncthreads(); }
    if (t == 0) lsek[b] = m + logf(sm[0] + NPAD * expf(0.0f - m));
}

// ================================================= skinny-N=32 fp32-A MFMA GEMM (no cvt pass)
template<int MODE>
__global__ __launch_bounds__(128) void k_sk32(const float* __restrict__ A1,
                                              const float* __restrict__ A2,
                                              const u16* __restrict__ Bsk,
                                              float* __restrict__ outp) {
    const int lane = threadIdx.x & 63;
    const int w = threadIdx.x >> 6;
    const int lrow = lane & 15;
    const int kg = lane >> 4;
    constexpr int K = (MODE == 0) ? 2048 : 1024;
    constexpr int bc0 = (MODE == 0) ? 0 : 1024;
    const int rowmax = (MODE == 0) ? (VOC - 1) : (KSN - 1);
    const int vb = blockIdx.x * 64 + w * 32;
    const int r0 = min(vb + lrow, rowmax);
    const int r1 = min(vb + 16 + lrow, rowmax);
    f32x4 acc[2][2] = {{{0.f,0.f,0.f,0.f},{0.f,0.f,0.f,0.f}},
                       {{0.f,0.f,0.f,0.f},{0.f,0.f,0.f,0.f}}};
    for (int k0 = 0; k0 < K; k0 += 32) {
        int kc = k0 + kg * 8;
        const float* s0;
        const float* s1;
        if (MODE == 0 && k0 >= 1024) {
            s0 = A2 + (size_t)r0 * 1024 + (kc - 1024);
            s1 = A2 + (size_t)r1 * 1024 + (kc - 1024);
        } else {
            s0 = A1 + (size_t)r0 * 1024 + kc;
            s1 = A1 + (size_t)r1 * 1024 + kc;
        }
        bf16x8 af0 = pack8(*(const float4*)s0, *(const float4*)(s0 + 4));
        bf16x8 af1 = pack8(*(const float4*)s1, *(const float4*)(s1 + 4));
        bf16x8 b0 = *(const bf16x8*)(Bsk + (size_t)lrow * 2048 + bc0 + kc);
        bf16x8 b1 = *(const bf16x8*)(Bsk + (size_t)(16 + lrow) * 2048 + bc0 + kc);
        acc[0][0] = __builtin_amdgcn_mfma_f32_16x16x32_bf16(af0, b0, acc[0][0], 0, 0, 0);
        acc[0][1] = __builtin_amdgcn_mfma_f32_16x16x32_bf16(af0, b1, acc[0][1], 0, 0, 0);
        acc[1][0] = __builtin_amdgcn_mfma_f32_16x16x32_bf16(af1, b0, acc[1][0], 0, 0, 0);
        acc[1][1] = __builtin_amdgcn_mfma_f32_16x16x32_bf16(af1, b1, acc[1][1], 0, 0, 0);
    }
    const int rg = kg * 4;
#pragma unroll
    for (int mi = 0; mi < 2; ++mi)
#pragma unroll
        for (int ni = 0; ni < 2; ++ni)
#pragma unroll
            for (int r = 0; r < 4; ++r) {
                int v = vb + mi * 16 + rg + r;
                int b = ni * 16 + lrow;
                if (MODE == 0) outp[(size_t)b * VOCP2 + v] = acc[mi][ni][r];
                else if (v < KSN) outp[(size_t)b * KSN + v] = acc[mi][ni][r];
            }
}

// ================================================= templated bf16 MFMA GEMM 128-tile
// EPI 0: GI (+bias, fp32)  EPI 1: MX maxout
template<int EPI>
__global__ __launch_bounds__(256) void gemm_bt(
    const u16* __restrict__ A, int lda,
    const u16* __restrict__ B, int ldb, int K,
    const float* __restrict__ p0, const float* __restrict__ p1,
    float* __restrict__ q0, u16* __restrict__ q1)
{
    __shared__ u16 Asm[128 * 64];
    __shared__ u16 Bsm[128 * 64];
    const int tid = threadIdx.x;
    const int lane = tid & 63;
    const int w = tid >> 6;
    const int wm = w >> 1, wn = w & 1;
    const int nt = blockIdx.x, mt = blockIdx.y;

    f32x4 acc[4][4];
#pragma unroll
    for (int i = 0; i < 4; ++i)
#pragma unroll
        for (int j = 0; j < 4; ++j) acc[i][j] = (f32x4){0.f, 0.f, 0.f, 0.f};

    for (int kt = 0; kt < K; kt += 64) {
#pragma unroll
        for (int p = 0; p < 4; ++p) {
            int flat = (w * 4 + p) * 64 + lane;       // 0..1023 16B-slots
            int row = flat >> 3, slot = flat & 7;
            int ss = slot ^ (row & 7);                // inverse-swizzled source slot
            gload_lds16(A + (size_t)(mt * 128 + row) * lda + kt + ss * 8, Asm + flat * 8);
            gload_lds16(B + (size_t)(nt * 128 + row) * ldb + kt + ss * 8, Bsm + flat * 8);
        }
        __syncthreads();
#pragma unroll
        for (int kc = 0; kc < 2; ++kc) {
            bf16x8 af[4], bfr[4];
#pragma unroll
            for (int mi = 0; mi < 4; ++mi) {
                int row = wm * 64 + mi * 16 + (lane & 15);
                int bcol = kc * 64 + ((lane >> 4) << 4);
                af[mi] = *(const bf16x8*)((const char*)Asm + row * 128 + (bcol ^ ((row & 7) << 4)));
            }
#pragma unroll
            for (int ni = 0; ni < 4; ++ni) {
                int row = wn * 64 + ni * 16 + (lane & 15);
                int bcol = kc * 64 + ((lane >> 4) << 4);
                bfr[ni] = *(const bf16x8*)((const char*)Bsm + row * 128 + (bcol ^ ((row & 7) << 4)));
            }
#pragma unroll
            for (int mi = 0; mi < 4; ++mi)
#pragma unroll
                for (int ni = 0; ni < 4; ++ni)
                    acc[mi][ni] = __builtin_amdgcn_mfma_f32_16x16x32_bf16(af[mi], bfr[ni], acc[mi][ni], 0, 0, 0);
        }
        __syncthreads();
    }

    const int cl = lane & 15;           // n offset within fragment
    const int rg = (lane >> 4) << 2;    // m base within fragment

    if constexpr (EPI == 0) {           // GI = TE@Wih.T + bih  (fp32 [n][3072])
#pragma unroll
        for (int mi = 0; mi < 4; ++mi) {
            int m0 = mt * 128 + wm * 64 + mi * 16 + rg;
            float4 bias = *(const float4*)(p0 + m0);
#pragma unroll
            for (int ni = 0; ni < 4; ++ni) {
                int n = nt * 128 + wn * 64 + ni * 16 + cl;
                float4 v;
                v.x = acc[mi][ni][0] + bias.x; v.y = acc[mi][ni][1] + bias.y;
                v.z = acc[mi][ni][2] + bias.z; v.w = acc[mi][ni][3] + bias.w;
                *(float4*)(q0 + (size_t)n * 3072 + m0) = v;
            }
        }
    }
    if constexpr (EPI == 1) {           // maxout -> BL bf16 [n][512]
#pragma unroll
        for (int mi = 0; mi < 4; ++mi) {
            int m0 = mt * 128 + wm * 64 + mi * 16 + rg;
            float4 eb4 = *(const float4*)(p1 + m0);
#pragma unroll
            for (int ni = 0; ni < 4; ++ni) {
                int n = nt * 128 + wn * 64 + ni * 16 + cl;
                int b = n >> 6;
                float v0 = acc[mi][ni][0] + p0[b * 1024 + m0 + 0] + eb4.x;
                float v1 = acc[mi][ni][1] + p0[b * 1024 + m0 + 1] + eb4.y;
                float v2 = acc[mi][ni][2] + p0[b * 1024 + m0 + 2] + eb4.z;
                float v3 = acc[mi][ni][3] + p0[b * 1024 + m0 + 3] + eb4.w;
                unsigned pk = f2bf(fmaxf(v0, v1)) | ((unsigned)f2bf(fmaxf(v2, v3)) << 16);
                *(unsigned*)(q1 + (size_t)n * 512 + (m0 >> 1)) = pk;
            }
        }
    }
}

// ================================================= FUSED 256x256 gate+logit GEMM.
// Pass 1 (gate): 24 K-tiles A34[v][1536] x BG[n][1536] -> g8 u8.
// Pass 2 (logit): 8 K-tiles Aemb[v][512] x BL[n][512] -> Lb bf16 + softmax partials.
// Same pipeline as r12 (BK=64, 128KB LDS, 8 waves 2Mx4N, 128B rows, slot^(r&7),
// pre-issue counted lgkmcnt, minimal barriers, vmcnt(4) at P4/P8).
__global__ __launch_bounds__(512, 1) void gemm_fused(
    const u16* __restrict__ A34,    // [VOCP2][1536]
    const u16* __restrict__ Aemb,   // [VOCP2][512]
    const u16* __restrict__ BG,     // [2048][1536]
    const u16* __restrict__ BL,     // [2048][512]
    const float* __restrict__ gc2,  // [32][VOCP2]
    unsigned char* __restrict__ g8, // [2048][VOCP2]
    u16* __restrict__ Lb,           // [2048][VOCP2]
    float* __restrict__ pmax,       // [2048][NTMP]
    float* __restrict__ psum)       // [2048][NTMP]
{
    __shared__ __align__(16) char smem[131072];
    const int tid = threadIdx.x;
    const int lane = tid & 63;
    const int w = tid >> 6;
    const int wm = w >> 2;          // 0..1: M half
    const int wn = w & 3;           // 0..3: N quarter
    const int lrow = lane & 15;
    const int g = lane >> 4;

    // XCD-chunked bijective block swizzle: 1568 = 8 * 196
    int bid = blockIdx.x;
    int wg = (bid & 7) * 196 + (bid >> 3);
    int mt = wg >> 3;               // 0..195
    int nt = wg & 7;                // 0..7
    const size_t arow0 = (size_t)mt * 256;
    const size_t brow0 = (size_t)nt * 256;

    auto stage = [&](const u16* __restrict__ src0, int ld, int abase, int T, int h) {
        char* dst = smem + (T & 1) * 65536 + abase + h * 16384;
        const u16* src = src0 + ((abase ? brow0 : arow0) + h * 128) * (size_t)ld + T * 64;
#pragma unroll
        for (int q = 0; q < 2; ++q) {
            int flat = q * 512 + tid;
            int r = flat >> 3, s = flat & 7;
            int ss = s ^ (r & 7);
            gload_lds16(src + (size_t)r * ld + ss * 8, dst + flat * 16);
        }
    };

    f32x4 acc[8][4];
#pragma unroll
    for (int i = 0; i < 8; ++i)
#pragma unroll
        for (int j = 0; j < 4; ++j) acc[i][j] = (f32x4){0.f, 0.f, 0.f, 0.f};

    const char* Ab[2] = { smem + wm * 16384, smem + 65536 + wm * 16384 };
    const char* Bb[2] = { smem + 32768 + (wn >> 1) * 16384,
                          smem + 65536 + 32768 + (wn >> 1) * 16384 };
    bf16x8 bf[4][2];
    bf16x8 afA[2][2], afB[2][2];

#define ISSA(D, Q, AF)                                                                \
    _Pragma("unroll") for (int mi = 0; mi < 2; ++mi) {                                \
        int r = ((Q) * 2 + mi) * 16 + lrow;                                           \
        _Pragma("unroll") for (int kk = 0; kk < 2; ++kk)                              \
            AF[mi][kk] = *(const bf16x8*)(Ab[D] + r * 128 +                           \
                            ((kk * 64 + g * 16) ^ ((r & 7) << 4)));                   \
    }
#define ISSB(D)                                                                       \
    _Pragma("unroll") for (int ni = 0; ni < 4; ++ni) {                                \
        int r = (wn & 1) * 64 + ni * 16 + lrow;                                       \
        _Pragma("unroll") for (int kk = 0; kk < 2; ++kk)                              \
            bf[ni][kk] = *(const bf16x8*)(Bb[D] + r * 128 +                           \
                            ((kk * 64 + g * 16) ^ ((r & 7) << 4)));                   \
    }
#define MM(Q, AF)                                                                     \
    __builtin_amdgcn_s_setprio(1);                                                    \
    _Pragma("unroll") for (int kk = 0; kk < 2; ++kk)                                  \
        _Pragma("unroll") for (int mi = 0; mi < 2; ++mi)                              \
            _Pragma("unroll") for (int ni = 0; ni < 4; ++ni)                          \
                acc[(Q) * 2 + mi][ni] = __builtin_amdgcn_mfma_f32_16x16x32_bf16(      \
                    AF[mi][kk], bf[ni][kk], acc[(Q) * 2 + mi][ni], 0, 0, 0);          \
    __builtin_amdgcn_s_setprio(0)
#define LG4 asm volatile("s_waitcnt lgkmcnt(4)" ::: "memory"); __builtin_amdgcn_sched_barrier(0)
#define LG0 asm volatile("s_waitcnt lgkmcnt(0)" ::: "memory"); __builtin_amdgcn_sched_barrier(0)
#define BARR  __builtin_amdgcn_sched_barrier(0); __builtin_amdgcn_s_barrier(); \
              __builtin_amdgcn_sched_barrier(0)
#define VM4 asm volatile("s_waitcnt vmcnt(4)" ::: "memory"); __builtin_amdgcn_sched_barrier(0)
#define VM0 asm volatile("s_waitcnt vmcnt(0)" ::: "memory"); __builtin_amdgcn_sched_barrier(0)
#define SA34(T, h)  stage(A34, 1536, 0, T, h)
#define SBG(T, h)   stage(BG, 1536, 32768, T, h)
#define SAE(T, h)   stage(Aemb, 512, 0, T, h)
#define SBL(T, h)   stage(BL, 512, 32768, T, h)

    // ---------------- PASS 1: gate (24 K-tiles) ----------------
    SBG(0, 0); SBG(0, 1); SA34(0, 0); SA34(0, 1); SBG(1, 0); SBG(1, 1);
    VM4; BARR;
    ISSA(0, 0, afA);
    for (int i = 0; i < 11; ++i) {
        int T0 = 2 * i, T1 = 2 * i + 1;
        SA34(T1, 0); ISSB(0); ISSA(0, 1, afB); LG4; MM(0, afA);
        SA34(T1, 1); ISSA(0, 2, afA); LG4; MM(1, afB);
        BARR;
        SBG(T0 + 2, 0); ISSA(0, 3, afB); LG4; MM(2, afA);
        SBG(T0 + 2, 1); VM4; ISSA(1, 0, afA); LG4; MM(3, afB);
        BARR;
        SA34(T0 + 2, 0); ISSB(1); ISSA(1, 1, afB); LG4; MM(0, afA);
        SA34(T0 + 2, 1); ISSA(1, 2, afA); LG4; MM(1, afB);
        BARR;
        SBG(T1 + 2, 0); ISSA(1, 3, afB); LG4; MM(2, afA);
        SBG(T1 + 2, 1); VM4; ISSA(0, 0, afA); LG4; MM(3, afB);
        BARR;
    }
    // peeled last gate iteration (tiles 22,23)
    SA34(23, 0); ISSB(0); ISSA(0, 1, afB); LG4; MM(0, afA);
    SA34(23, 1); ISSA(0, 2, afA); LG4; MM(1, afB);
    BARR;
    ISSA(0, 3, afB); LG4; MM(2, afA);
    VM0; ISSA(1, 0, afA); LG4; MM(3, afB);
    BARR;
    ISSB(1); ISSA(1, 1, afB); LG4; MM(0, afA);
    ISSA(1, 2, afA); LG4; MM(1, afB);
    ISSA(1, 3, afB); LG4; MM(2, afA);
    LG0; MM(3, afB);

    // ---- gate epilogue: g8 = u8(sigmoid(acc + gc))
    {
        const int rg = g << 2;
        const int b = nt * 4 + wn;
        const float* gcrow = gc2 + (size_t)b * VOCP2;
#pragma unroll
        for (int m = 0; m < 8; ++m) {
            int v0 = mt * 256 + wm * 128 + m * 16 + rg;
            float4 gcv = *(const float4*)(gcrow + v0);
#pragma unroll
            for (int ni = 0; ni < 4; ++ni) {
                int n = nt * 256 + wn * 64 + ni * 16 + lrow;
                unsigned pk = 0;
#pragma unroll
                for (int r = 0; r < 4; ++r) {
                    float garg = acc[m][ni][r] + ((const float*)&gcv)[r];
                    float gate = 1.0f / (1.0f + expf(-garg));
                    pk |= ((unsigned)(int)(gate * 255.0f + 0.5f)) << (8 * r);
                }
                *(unsigned*)(g8 + (size_t)n * VOCP2 + v0) = pk;
            }
        }
    }
    BARR;                               // all waves done reading LDS before re-staging

    // ---------------- PASS 2: logit (8 K-tiles, K=512) ----------------
#pragma unroll
    for (int i = 0; i < 8; ++i)
#pragma unroll
        for (int j = 0; j < 4; ++j) acc[i][j] = (f32x4){0.f, 0.f, 0.f, 0.f};

    SBL(0, 0); SBL(0, 1); SAE(0, 0); SAE(0, 1); SBL(1, 0); SBL(1, 1);
    VM4; BARR;                          // waits include draining g8 stores — safe
    ISSA(0, 0, afA);
    for (int i = 0; i < 3; ++i) {
        int T0 = 2 * i, T1 = 2 * i + 1;
        SAE(T1, 0); ISSB(0); ISSA(0, 1, afB); LG4; MM(0, afA);
        SAE(T1, 1); ISSA(0, 2, afA); LG4; MM(1, afB);
        BARR;
        SBL(T0 + 2, 0); ISSA(0, 3, afB); LG4; MM(2, afA);
        SBL(T0 + 2, 1); VM4; ISSA(1, 0, afA); LG4; MM(3, afB);
        BARR;
        SAE(T0 + 2, 0); ISSB(1); ISSA(1, 1, afB); LG4; MM(0, afA);
        SAE(T0 + 2, 1); ISSA(1, 2, afA); LG4; MM(1, afB);
        BARR;
        SBL(T1 + 2, 0); ISSA(1, 3, afB); LG4; MM(2, afA);
        SBL(T1 + 2, 1); VM4; ISSA(0, 0, afA); LG4; MM(3, afB);
        BARR;
    }
    // peeled last logit iteration (tiles 6,7)
    SAE(7, 0); ISSB(0); ISSA(0, 1, afB); LG4; MM(0, afA);
    SAE(7, 1); ISSA(0, 2, afA); LG4; MM(1, afB);
    BARR;
    ISSA(0, 3, afB); LG4; MM(2, afA);
    VM0; ISSA(1, 0, afA); LG4; MM(3, afB);
    BARR;
    ISSB(1); ISSA(1, 1, afB); LG4; MM(0, afA);
    ISSA(1, 2, afA); LG4; MM(1, afB);
    ISSA(1, 3, afB); LG4; MM(2, afA);
    LG0; MM(3, afB);

    // ---- logit epilogue: Lb bf16 + per-(n, mt) softmax partials
    BARR;                               // LDS free for reduction scratch
    {
        const int rg = g << 2;
        // Lb writes
#pragma unroll
        for (int m = 0; m < 8; ++m) {
            int v0 = mt * 256 + wm * 128 + m * 16 + rg;
#pragma unroll
            for (int ni = 0; ni < 4; ++ni) {
                int n = nt * 256 + wn * 64 + ni * 16 + lrow;
                unsigned lo = f2bf(acc[m][ni][0]) | ((unsigned)f2bf(acc[m][ni][1]) << 16);
                unsigned hi = f2bf(acc[m][ni][2]) | ((unsigned)f2bf(acc[m][ni][3]) << 16);
                *(uint2*)(Lb + (size_t)n * VOCP2 + v0) = make_uint2(lo, hi);
            }
        }
        // partial max / sumexp over this block's 256 v-rows (masked v<VOC)
        float* redm = (float*)smem;            // [2][256]
        float* reds = (float*)(smem + 2048);   // [2][256]
#pragma unroll
        for (int ni = 0; ni < 4; ++ni) {
            float lm = -1e30f;
#pragma unroll
            for (int m = 0; m < 8; ++m) {
                int v0 = mt * 256 + wm * 128 + m * 16 + rg;
#pragma unroll
                for (int r = 0; r < 4; ++r)
                    if (v0 + r < VOC) lm = fmaxf(lm, acc[m][ni][r]);
            }
            lm = fmaxf(lm, __shfl_xor(lm, 16));
            lm = fmaxf(lm, __shfl_xor(lm, 32));
            float s = 0.0f;
#pragma unroll
            for (int m = 0; m < 8; ++m) {
                int v0 = mt * 256 + wm * 128 + m * 16 + rg;
#pragma unroll
                for (int r = 0; r < 4; ++r)
                    if (v0 + r < VOC) s += expf(acc[m][ni][r] - lm);
            }
            s += __shfl_xor(s, 16);
            s += __shfl_xor(s, 32);
            if (lane < 16) {
                redm[wm * 256 + wn * 64 + ni * 16 + lane] = lm;
                reds[wm * 256 + wn * 64 + ni * 16 + lane] = s;
            }
        }
        BARR;
        if (tid < 256) {
            float m0_ = redm[tid], m1_ = redm[256 + tid];
            float m = fmaxf(m0_, m1_);
            float s = reds[tid] * expf(m0_ - m) + reds[256 + tid] * expf(m1_ - m);
            int n = nt * 256 + tid;
            pmax[(size_t)n * NTMP + mt] = m;
            psum[(size_t)n * NTMP + mt] = s;
        }
    }
#undef ISSA
#undef ISSB
#undef MM
#undef LG4
#undef LG0
#undef BARR
#undef VM4
#undef VM0
#undef SA34
#undef SBG
#undef SAE
#undef SBL
}

// ------------------------------------------------- persistent MFMA GRU v5
// 64 blocks x 256 threads. A panel (48x1024 bf16 = 96 KB) resident; per step ALL of
// the wave's h (32x256 = 16 KB/wave, 4 chunk regions) staged up front with ONE
// vmcnt(0) wait — no mid-loop waits. LDS = 96 + 64 = 160 KiB (full pool).
__global__ __launch_bounds__(256, 1) void k_gru_m5(const u16* __restrict__ WhhB,
                                                   const float* __restrict__ GI,
                                                   const float* __restrict__ bhh,
                                                   const u16* __restrict__ h0b,
                                                   u16* __restrict__ BG,
                                                   unsigned* __restrict__ flags) {
    __shared__ __align__(16) char smem[163840];
    const int tid = threadIdx.x;
    const int lane = tid & 63;
    const int w = tid >> 6;
    const int jb = blockIdx.x;            // 0..63
    const int j0 = jb * 16;
    const int jl = tid & 15, bp = tid >> 4;
    const int je = j0 + jl;
    const float bh0 = bhh[je], bh1 = bhh[1024 + je], bh2 = bhh[2048 + je];
    char* Bbase = smem + 98304 + w * 16384;

#pragma unroll
    for (int it = 0; it < 24; ++it) {
        int flat = (it * 4 + w) * 64 + lane;
        int r = flat >> 7, s = flat & 127;
        int ss = s ^ (r & 7);
        int gr = (r >> 4) * 1024 + j0 + (r & 15);
        gload_lds16(WhhB + (size_t)gr * 1024 + ss * 8, smem + (size_t)flat * 16);
    }

    float hpv[2];
#pragma unroll
    for (int rb = 0; rb < 2; ++rb)
        hpv[rb] = bf2f(h0b[(size_t)(bp * 2 + rb) * 1024 + je]);

    const int lrow = lane & 15;
    const int ksel = lane >> 4;

    for (int t = 0; t < 64; ++t) {
        const u16* hsrc = (t == 0) ? h0b : BG + (size_t)(t - 1) * 1536;
        const size_t hstr = (t == 0) ? 1024 : (size_t)64 * 1536;

        // stage ALL 4 chunks of this wave's h K-range (16 gload_lds)
#pragma unroll
        for (int c = 0; c < 4; ++c) {
            char* dst = Bbase + c * 4096;
            int kq0 = w * 256 + c * 64;
#pragma unroll
            for (int q = 0; q < 4; ++q) {
                int flat = q * 64 + lane;
                int r = flat >> 3, s = flat & 7;
                int ss = s ^ (r & 7);
                gload_lds16x<0x11>(hsrc + (size_t)r * hstr + kq0 + ss * 8,
                                   dst + (size_t)flat * 16);
            }
        }
        // GI prefetch (latency hides under the stage wait)
        float gi0[2], gi1[2], gi2[2];
#pragma unroll
        for (int rb = 0; rb < 2; ++rb) {
            const float* gp = GI + ((size_t)((bp * 2 + rb) * 64 + t)) * 3072 + je;
            gi0[rb] = gp[0]; gi1[rb] = gp[1024]; gi2[rb] = gp[2048];
        }
        if (t == 0) {
            __syncthreads();              // drains A panel + stages + GI
        } else {
            asm volatile("s_waitcnt vmcnt(0)" ::: "memory");
        }
        __builtin_amdgcn_sched_barrier(0);

        f32x4 acc[3][2];
#pragma unroll
        for (int mi = 0; mi < 3; ++mi)
#pragma unroll
            for (int ni = 0; ni < 2; ++ni) acc[mi][ni] = (f32x4){0.f, 0.f, 0.f, 0.f};

#pragma unroll
        for (int c = 0; c < 4; ++c) {
            char* Bb = Bbase + c * 4096;
#pragma unroll
            for (int ks = 0; ks < 2; ++ks) {
                int kb = ks * 64 + ksel * 16;
                bf16x8 bfr[2];
#pragma unroll
                for (int ni = 0; ni < 2; ++ni) {
                    int br = ni * 16 + lrow;
                    bfr[ni] = *(const bf16x8*)(Bb + br * 128 + (kb ^ ((br & 7) << 4)));
                }
                int kA = w * 512 + c * 128 + kb;
#pragma unroll
                for (int mi = 0; mi < 3; ++mi) {
                    int ar = mi * 16 + lrow;
                    bf16x8 af = *(const bf16x8*)(smem + ar * 2048 + (kA ^ ((ar & 7) << 4)));
#pragma unroll
                    for (int ni = 0; ni < 2; ++ni)
                        acc[mi][ni] = __builtin_amdgcn_mfma_f32_16x16x32_bf16(af, bfr[ni], acc[mi][ni], 0, 0, 0);
                }
            }
        }

        // cross-wave K-reduction via per-wave epi (aliases own B region)
        float (*epiw)[33] = (float(*)[33])Bbase;
        asm volatile("s_waitcnt lgkmcnt(0)" ::: "memory");   // B reads done before alias write
        __builtin_amdgcn_sched_barrier(0);
        {
            const int rg = (lane >> 4) << 2;
#pragma unroll
            for (int mi = 0; mi < 3; ++mi)
#pragma unroll
                for (int ni = 0; ni < 2; ++ni) {
                    int m0 = mi * 16 + rg;
                    int cb = ni * 16 + lrow;
#pragma unroll
                    for (int r = 0; r < 4; ++r) epiw[m0 + r][cb] = acc[mi][ni][r];
                }
        }
        asm volatile("s_waitcnt lgkmcnt(0)" ::: "memory");
        __builtin_amdgcn_s_barrier();

#pragma unroll
        for (int rb = 0; rb < 2; ++rb) {
            int b = bp * 2 + rb;
            float s0 = 0.f, s1 = 0.f, s2 = 0.f;
#pragma unroll
            for (int ww = 0; ww < 4; ++ww) {
                float (*ep)[33] = (float(*)[33])(smem + 98304 + ww * 16384);
                s0 += ep[jl][b]; s1 += ep[16 + jl][b]; s2 += ep[32 + jl][b];
            }
            float rr = sigmoidf_(gi0[rb] + s0 + bh0);
            float zz = sigmoidf_(gi1[rb] + s1 + bh1);
            float nn = tanhf(gi2[rb] + rr * (s2 + bh2));
            float hnew = (1.0f - zz) * nn + zz * hpv[rb];
            hpv[rb] = hnew;
            store_u16_sc(BG + ((size_t)(b * 64 + t)) * 1536 + je, f2bf(hnew));
        }

        if (t < 63) {
            asm volatile("s_waitcnt vmcnt(0)" ::: "memory");   // h stores at coherence point
            __syncthreads();                                   // epi reads + stores complete
            if (tid == 0)
                __hip_atomic_store(&flags[jb], (unsigned)(t + 1),
                                   __ATOMIC_RELAXED, __HIP_MEMORY_SCOPE_AGENT);
            unsigned tgt = (unsigned)(t + 1);
            while (true) {
                unsigned v = __hip_atomic_load(&flags[lane],
                                               __ATOMIC_RELAXED, __HIP_MEMORY_SCOPE_AGENT);
                if (__all(v >= tgt)) break;
                __builtin_amdgcn_s_sleep(1);
            }
            __builtin_amdgcn_sched_barrier(0);
        }
    }
}

// ------------------------------------------------- per-row lse from partials (196 tiles)
__global__ __launch_bounds__(256) void k_lse(const float* __restrict__ pmax,
                                             const float* __restrict__ psum,
                                             float* __restrict__ lse) {
    int n = blockIdx.x;
    int t = threadIdx.x;
    __shared__ float sm[256];
    const float* pm = pmax + (size_t)n * NTMP;
    const float* ps = psum + (size_t)n * NTMP;
    float m = -1e30f;
    if (t < NT2) m = pm[t];
    sm[t] = m;
    __syncthreads();
    for (int s = 128; s > 0; s >>= 1) { if (t < s) sm[t] = fmaxf(sm[t], sm[t + s]); __syncthreads(); }
    m = sm[0];
    __syncthreads();
    float s = 0.0f;
    if (t < NT2) s = ps[t] * expf(pm[t] - m);
    sm[t] = s;
    __syncthreads();
    for (int r = 128; r > 0; r >>= 1) { if (t < r) sm[t] += sm[t + r]; __syncthreads(); }
    if (t == 0) lse[n] = m + logf(sm[0]);
}

// ------------------------------------------------- final combine (fully coalesced)
__global__ __launch_bounds__(256) void k_final(const u16* __restrict__ Lb,
                                               const unsigned char* __restrict__ g8,
                                               const float* __restrict__ lse,
                                               const float* __restrict__ ks,
                                               const float* __restrict__ lsek,
                                               float* __restrict__ out) {
    int n = blockIdx.y;
    int b = n >> 6;
    float lsen = lse[n], lkb = lsek[b];
    int base = blockIdx.x * 2048;
#pragma unroll
    for (int i = 0; i < 8; ++i) {
        int v = base + i * 256 + threadIdx.x;
        if (v < VOC) {
            float L = bf2f(Lb[(size_t)n * VOCP2 + v]);
            float g = g8[(size_t)n * VOCP2 + v] * (1.0f / 255.0f);
            float kp = ((v >= 10 && v < 10 + KSN) ? ks[(size_t)b * KSN + (v - 10)] : 0.0f) - lkb;
            out[(size_t)n * VOC + v] = g * (L - lsen) + (1.0f - g) * kp;
        }
    }
}

// ---------------------------------------------------------------- launch
extern "C" void kernel_launch(void* const* d_in, const int* in_sizes, int n_in,
                              void* d_out, int out_size, void* d_ws, size_t ws_size,
                              hipStream_t stream) {
    const float* ses    = (const float*)d_in[0];
    const float* know   = (const float*)d_in[1];
    const int*   target = (const int*)d_in[2];
    const float* embed  = (const float*)d_in[3];
    const float* Wih    = (const float*)d_in[4];
    const float* Whh    = (const float*)d_in[5];
    const float* bih    = (const float*)d_in[6];
    const float* bhh    = (const float*)d_in[7];
    const float* sdw    = (const float*)d_in[8];
    const float* sdb    = (const float*)d_in[9];
    const float* dw     = (const float*)d_in[10];
    const float* siw    = (const float*)d_in[11];
    const float* ew     = (const float*)d_in[12];
    const float* eb     = (const float*)d_in[13];
    const float* W1     = (const float*)d_in[14];
    const float* W2     = (const float*)d_in[15];
    const float* W3     = (const float*)d_in[16];
    const float* W4     = (const float*)d_in[17];
    const float* kvw    = (const float*)d_in[18];

    char* ws = (char*)d_ws;
    size_t o = 0;
    auto alloc = [&](size_t bytes) { char* r = ws + o; o += (bytes + 255) & ~(size_t)255; return r; };
    u16*   Aemb  = (u16*)  alloc((size_t)VOCP2 * 512 * 2);
    u16*   A34   = (u16*)  alloc((size_t)VOCP2 * 1536 * 2);
    u16*   Adwew = (u16*)  alloc((size_t)1024 * 1536 * 2);
    u16*   Wihb  = (u16*)  alloc((size_t)3072 * 512 * 2);
    u16*   WhhB  = (u16*)  alloc((size_t)3072 * 1024 * 2);
    u16*   h0b   = (u16*)  alloc((size_t)32 * 1024 * 2);
    u16*   BG    = (u16*)  alloc((size_t)2048 * 1536 * 2);
    u16*   BL    = (u16*)  alloc((size_t)2048 * 512 * 2);
    float* GI    = (float*)alloc((size_t)2048 * 3072 * 4);
    float* h0    = (float*)alloc((size_t)32 * 1024 * 4);
    float* sesinf= (float*)alloc((size_t)32 * 1024 * 4);
    float* gc    = (float*)alloc((size_t)32 * VOCP2 * 4);
    float* ksb   = (float*)alloc((size_t)32 * KSN * 4);
    float* lsek  = (float*)alloc(256);
    float* lse   = (float*)alloc((size_t)2048 * 4);
    unsigned* flags = (unsigned*)alloc(256);
    float* pmax  = (float*)alloc((size_t)2048 * NTMP * 4);
    float* psum  = (float*)alloc((size_t)2048 * NTMP * 4);
    unsigned char* g8 = (unsigned char*)alloc((size_t)2048 * VOCP2);
    u16*   Lb    = (u16*)  alloc((size_t)2048 * VOCP2 * 2);
    u16*   Bsk   = (u16*)  alloc((size_t)128 * 2048 * 2);
    float* out = (float*)d_out;

    hipMemsetAsync(flags, 0, 256, stream);

    // weight conversions (W1/W2/kvw consumed fp32 by k_sk32)
    k_cvt<<<dim3(VOC, 1), 256, 0, stream>>>(embed, Aemb, 512, 512, 512);
    k_cvt<<<dim3(VOC, 1), 256, 0, stream>>>(W3, A34, 1024, 1024, 1536);
    k_cvt<<<dim3(VOC, 1), 256, 0, stream>>>(W4, A34 + 1024, 512, 512, 1536);
    k_pad0<<<dim3(VOCP2 - VOC), 256, 0, stream>>>(Aemb, A34);
    k_cvt<<<dim3(1024, 1), 256, 0, stream>>>(dw, Adwew, 1024, 1024, 1536);
    k_cvt<<<dim3(1024, 1), 256, 0, stream>>>(ew, Adwew + 1024, 512, 512, 1536);
    k_cvt<<<dim3(3072, 1), 256, 0, stream>>>(Wih, Wihb, 512, 512, 512);
    k_cvt<<<dim3(3072, 1), 256, 0, stream>>>(Whh, WhhB, 1024, 1024, 1024);
    k_bsk<<<dim3(128), 256, 0, stream>>>(ses, know, Bsk);

    k_gather<<<dim3(2048), 128, 0, stream>>>(embed, target, BG);
    k_h0_sesinf<<<dim3(32), 256, 0, stream>>>(ses, sdw, sdb, siw, h0, sesinf);
    k_cvt<<<dim3(32, 1), 256, 0, stream>>>(h0, h0b, 1024, 1024, 1024);

    // gc = [ses|know]·[W1|W2]^T  (fp32-A skinny MFMA, VOCP2 stride)
    k_sk32<0><<<dim3(VOCP2 / 64), 128, 0, stream>>>(W1, W2, Bsk, gc);
    // ks = know·kvw^T
    k_sk32<1><<<dim3((KSN + 63) / 64), 128, 0, stream>>>(kvw, nullptr, Bsk, ksb);
    k_lseknow<<<dim3(32), 256, 0, stream>>>(ksb, lsek);

    // GI = TE @ Wih.T + bih
    gemm_bt<0><<<dim3(16, 24), 256, 0, stream>>>(Wihb, 512, BG + 1024, 1536, 512,
                                                 bih, nullptr, GI, nullptr);
    // GRU recurrence: persistent kernel, single-wait staging, 160 KiB LDS
    k_gru_m5<<<dim3(64), 256, 0, stream>>>(WhhB, GI, bhh, h0b, BG, flags);
    // MX (maxout) -> BL
    gemm_bt<1><<<dim3(16, 8), 256, 0, stream>>>(Adwew, 1536, BG, 1536, 1536,
                                                sesinf, eb, nullptr, BL);
    // FUSED gate + logit GEMM -> g8, Lb, partials
    gemm_fused<<<dim3(1568), 512, 0, stream>>>(A34, Aemb, BG, BL, gc, g8, Lb, pmax, psum);
    k_lse<<<dim3(2048), 256, 0, stream>>>(pmax, psum, lse);
    k_final<<<dim3(25, 2048), 256, 0, stream>>>(Lb, g8, lse, ksb, lsek, out);
}

// Round 15
// 1589.366 us; speedup vs baseline: 1.0037x; 1.0037x over previous
//
#include <hip/hip_runtime.h>

// Problem dims
constexpr int VOC  = 50005;
constexpr int VOCP = 50048;   // 391*128, padded vocab (128-tile GEMMs)
constexpr int VOCP2= 50176;   // 196*256, padded vocab (256-tile GEMM)
constexpr int NTM  = 391;     // vocab tiles (128) for logit GEMM
constexpr int NTMP = 400;     // padded partial stride
constexpr int KSN  = 8784;    // KNOW-1
constexpr float NPAD = 41221.0f;

typedef unsigned short u16;
typedef __attribute__((ext_vector_type(4))) float f32x4;
typedef __attribute__((ext_vector_type(8))) short bf16x8;

__device__ __forceinline__ float dot4(float4 a, float4 b) {
    return a.x*b.x + a.y*b.y + a.z*b.z + a.w*b.w;
}
__device__ __forceinline__ float sigmoidf_(float x) { return 1.0f / (1.0f + expf(-x)); }
__device__ __forceinline__ u16 f2bf(float f) {
    unsigned x = __float_as_uint(f);
    return (u16)((x + 0x7FFFu + ((x >> 16) & 1u)) >> 16);
}
__device__ __forceinline__ float bf2f(u16 u) { return __uint_as_float(((unsigned)u) << 16); }
__device__ __forceinline__ bf16x8 pack8(float4 lo, float4 hi) {
    union { bf16x8 v; unsigned u[4]; } r;
    r.u[0] = f2bf(lo.x) | ((unsigned)f2bf(lo.y) << 16);
    r.u[1] = f2bf(lo.z) | ((unsigned)f2bf(lo.w) << 16);
    r.u[2] = f2bf(hi.x) | ((unsigned)f2bf(hi.y) << 16);
    r.u[3] = f2bf(hi.z) | ((unsigned)f2bf(hi.w) << 16);
    return r.v;
}
template<int AUX>
__device__ __forceinline__ void gload_lds16x(const void* g, void* l) {
    __builtin_amdgcn_global_load_lds((const __attribute__((address_space(1))) unsigned int*)g,
                                     (__attribute__((address_space(3))) unsigned int*)l, 16, 0, AUX);
}
__device__ __forceinline__ void gload_lds16(const void* g, void* l) { gload_lds16x<0>(g, l); }
// device-coherent u16 store (write-through to coherence point, cross-XCD visible)
__device__ __forceinline__ void store_u16_sc(u16* p, u16 v) {
    asm volatile("global_store_short %0, %1, off sc0 sc1" :: "v"(p), "v"((unsigned)v) : "memory");
}

// ---------------------------------------------------------------- cvt fp32 -> bf16 (strided)
__global__ __launch_bounds__(256) void k_cvt(const float* __restrict__ src, u16* __restrict__ dst,
                                             int ncols, int sld, int dld) {
    int row = blockIdx.x;
    int c = (blockIdx.y * 256 + threadIdx.x) * 4;
    if (c >= ncols) return;
    float4 v = *(const float4*)(src + (size_t)row * sld + c);
    unsigned lo = f2bf(v.x) | ((unsigned)f2bf(v.y) << 16);
    unsigned hi = f2bf(v.z) | ((unsigned)f2bf(v.w) << 16);
    *(uint2*)(dst + (size_t)row * dld + c) = make_uint2(lo, hi);
}

// zero pad rows 50005..50175 of A34 (VOCP2), 50005..50047 of Aemb (VOCP)
__global__ __launch_bounds__(256) void k_pad0(u16* __restrict__ Aemb, u16* __restrict__ A34) {
    int r = VOC + blockIdx.x;            // 50005..50175
    unsigned* p3 = (unsigned*)(A34 + (size_t)r * 1536);
    for (int i = threadIdx.x; i < 768; i += 256) p3[i] = 0;
    if (r < VOCP) {
        unsigned* pe = (unsigned*)(Aemb + (size_t)r * 512);
        if (threadIdx.x < 256) pe[threadIdx.x] = 0;
    }
}

// build Bsk [128][2048] bf16: rows 0..31 = [ses|know], rows 32..127 = 0
__global__ __launch_bounds__(256) void k_bsk(const float* __restrict__ ses,
                                             const float* __restrict__ know,
                                             u16* __restrict__ Bsk) {
    int row = blockIdx.x;
    for (int c0 = threadIdx.x * 4; c0 < 2048; c0 += 1024) {
        uint2 val = make_uint2(0, 0);
        if (row < 32) {
            const float* srcp = (c0 < 1024) ? ses + (size_t)row * 1024 + c0
                                            : know + (size_t)row * 1024 + (c0 - 1024);
            float4 v = *(const float4*)srcp;
            val = make_uint2(f2bf(v.x) | ((unsigned)f2bf(v.y) << 16),
                             f2bf(v.z) | ((unsigned)f2bf(v.w) << 16));
        }
        *(uint2*)(Bsk + (size_t)row * 2048 + c0) = val;
    }
}

// ---------------------------------------------------------------- gather target embeddings -> BG[:,1024:1536] bf16
__global__ __launch_bounds__(128) void k_gather(const float* __restrict__ embed,
                                                const int* __restrict__ target,
                                                u16* __restrict__ BG) {
    int n = blockIdx.x;
    int row = target[n];
    int c = threadIdx.x * 4;
    float4 v = *(const float4*)(embed + (size_t)row * 512 + c);
    unsigned lo = f2bf(v.x) | ((unsigned)f2bf(v.y) << 16);
    unsigned hi = f2bf(v.z) | ((unsigned)f2bf(v.w) << 16);
    *(uint2*)(BG + (size_t)n * 1536 + 1024 + c) = make_uint2(lo, hi);
}

// ------------------------------------------------- h0 + ses_inf_vec (fp32, small)
__global__ __launch_bounds__(256) void k_h0_sesinf(const float* __restrict__ ses,
                                                   const float* __restrict__ sdw,
                                                   const float* __restrict__ sdb,
                                                   const float* __restrict__ siw,
                                                   float* __restrict__ h0,
                                                   float* __restrict__ sesinf) {
    int g = blockIdx.x * 256 + threadIdx.x;
    int b = g & 31;
    int jg = g >> 5;
    int j0 = jg * 4;
    const float4* s4 = (const float4*)(ses + (size_t)b * 1024);
    const float4* wa[4];
    const float4* wc[4];
#pragma unroll
    for (int r = 0; r < 4; ++r) {
        wa[r] = (const float4*)(sdw + (size_t)(j0 + r) * 1024);
        wc[r] = (const float4*)(siw + (size_t)(j0 + r) * 1024);
    }
    float a[4] = {0, 0, 0, 0}, c[4] = {0, 0, 0, 0};
    for (int kq = 0; kq < 256; ++kq) {
        float4 sv = s4[kq];
#pragma unroll
        for (int r = 0; r < 4; ++r) { a[r] += dot4(sv, wa[r][kq]); c[r] += dot4(sv, wc[r][kq]); }
    }
#pragma unroll
    for (int r = 0; r < 4; ++r) {
        h0[b * 1024 + j0 + r] = tanhf(a[r] + sdb[j0 + r]);
        sesinf[b * 1024 + j0 + r] = c[r];
    }
}

// ------------------------------------------------- lse of padded know scores
__global__ __launch_bounds__(256) void k_lseknow(const float* __restrict__ ks,
                                                 float* __restrict__ lsek) {
    int b = blockIdx.x;
    int t = threadIdx.x;
    __shared__ float sm[256];
    float m = -1e30f;
    for (int j = t; j < KSN; j += 256) m = fmaxf(m, ks[(size_t)b * KSN + j]);
    sm[t] = m;
    __syncthreads();
    for (int s = 128; s > 0; s >>= 1) { if (t < s) sm[t] = fmaxf(sm[t], sm[t + s]); __syncthreads(); }
    m = fmaxf(sm[0], 0.0f);
    __syncthreads();
    float s = 0.0f;
    for (int j = t; j < KSN; j += 256) s += expf(ks[(size_t)b * KSN + j] - m);
    sm[t] = s;
    __syncthreads();
    for (int r = 128; r > 0; r >>= 1) { if (t < r) sm[t] += sm[t + r]; __syncthreads(); }
    if (t == 0) lsek[b] = m + logf(sm[0] + NPAD * expf(0.0f - m));
}

// ================================================= skinny-N=32 fp32-A MFMA GEMM (no cvt pass)
template<int MODE>
__global__ __launch_bounds__(128) void k_sk32(const float* __restrict__ A1,
                                              const float* __restrict__ A2,
                                              const u16* __restrict__ Bsk,
                                              float* __restrict__ outp) {
    const int lane = threadIdx.x & 63;
    const int w = threadIdx.x >> 6;
    const int lrow = lane & 15;
    const int kg = lane >> 4;
    constexpr int K = (MODE == 0) ? 2048 : 1024;
    constexpr int bc0 = (MODE == 0) ? 0 : 1024;
    const int rowmax = (MODE == 0) ? (VOC - 1) : (KSN - 1);
    const int vb = blockIdx.x * 64 + w * 32;
    const int r0 = min(vb + lrow, rowmax);
    const int r1 = min(vb + 16 + lrow, rowmax);
    f32x4 acc[2][2] = {{{0.f,0.f,0.f,0.f},{0.f,0.f,0.f,0.f}},
                       {{0.f,0.f,0.f,0.f},{0.f,0.f,0.f,0.f}}};
    for (int k0 = 0; k0 < K; k0 += 32) {
        int kc = k0 + kg * 8;
        const float* s0;
        const float* s1;
        if (MODE == 0 && k0 >= 1024) {
            s0 = A2 + (size_t)r0 * 1024 + (kc - 1024);
            s1 = A2 + (size_t)r1 * 1024 + (kc - 1024);
        } else {
            s0 = A1 + (size_t)r0 * 1024 + kc;
            s1 = A1 + (size_t)r1 * 1024 + kc;
        }
        bf16x8 af0 = pack8(*(const float4*)s0, *(const float4*)(s0 + 4));
        bf16x8 af1 = pack8(*(const float4*)s1, *(const float4*)(s1 + 4));
        bf16x8 b0 = *(const bf16x8*)(Bsk + (size_t)lrow * 2048 + bc0 + kc);
        bf16x8 b1 = *(const bf16x8*)(Bsk + (size_t)(16 + lrow) * 2048 + bc0 + kc);
        acc[0][0] = __builtin_amdgcn_mfma_f32_16x16x32_bf16(af0, b0, acc[0][0], 0, 0, 0);
        acc[0][1] = __builtin_amdgcn_mfma_f32_16x16x32_bf16(af0, b1, acc[0][1], 0, 0, 0);
        acc[1][0] = __builtin_amdgcn_mfma_f32_16x16x32_bf16(af1, b0, acc[1][0], 0, 0, 0);
        acc[1][1] = __builtin_amdgcn_mfma_f32_16x16x32_bf16(af1, b1, acc[1][1], 0, 0, 0);
    }
    const int rg = kg * 4;
#pragma unroll
    for (int mi = 0; mi < 2; ++mi)
#pragma unroll
        for (int ni = 0; ni < 2; ++ni)
#pragma unroll
            for (int r = 0; r < 4; ++r) {
                int v = vb + mi * 16 + rg + r;
                int b = ni * 16 + lrow;
                if (MODE == 0) outp[(size_t)b * VOCP2 + v] = acc[mi][ni][r];
                else if (v < KSN) outp[(size_t)b * KSN + v] = acc[mi][ni][r];
            }
}

// ================================================= templated bf16 MFMA GEMM 128-tile
// EPI 0: GI (+bias, fp32)  EPI 1: MX maxout  EPI 3: logits+partials (Lb stride VOCP)
template<int EPI>
__global__ __launch_bounds__(256) void gemm_bt(
    const u16* __restrict__ A, int lda,
    const u16* __restrict__ B, int ldb, int K,
    const float* __restrict__ p0, const float* __restrict__ p1,
    float* __restrict__ q0, u16* __restrict__ q1, float* __restrict__ q3)
{
    __shared__ u16 Asm[128 * 64];
    __shared__ u16 Bsm[128 * 64];
    const int tid = threadIdx.x;
    const int lane = tid & 63;
    const int w = tid >> 6;
    const int wm = w >> 1, wn = w & 1;
    const int nt = blockIdx.x, mt = blockIdx.y;

    f32x4 acc[4][4];
#pragma unroll
    for (int i = 0; i < 4; ++i)
#pragma unroll
        for (int j = 0; j < 4; ++j) acc[i][j] = (f32x4){0.f, 0.f, 0.f, 0.f};

    for (int kt = 0; kt < K; kt += 64) {
#pragma unroll
        for (int p = 0; p < 4; ++p) {
            int flat = (w * 4 + p) * 64 + lane;       // 0..1023 16B-slots
            int row = flat >> 3, slot = flat & 7;
            int ss = slot ^ (row & 7);                // inverse-swizzled source slot
            gload_lds16(A + (size_t)(mt * 128 + row) * lda + kt + ss * 8, Asm + flat * 8);
            gload_lds16(B + (size_t)(nt * 128 + row) * ldb + kt + ss * 8, Bsm + flat * 8);
        }
        __syncthreads();
#pragma unroll
        for (int kc = 0; kc < 2; ++kc) {
            bf16x8 af[4], bfr[4];
#pragma unroll
            for (int mi = 0; mi < 4; ++mi) {
                int row = wm * 64 + mi * 16 + (lane & 15);
                int bcol = kc * 64 + ((lane >> 4) << 4);
                af[mi] = *(const bf16x8*)((const char*)Asm + row * 128 + (bcol ^ ((row & 7) << 4)));
            }
#pragma unroll
            for (int ni = 0; ni < 4; ++ni) {
                int row = wn * 64 + ni * 16 + (lane & 15);
                int bcol = kc * 64 + ((lane >> 4) << 4);
                bfr[ni] = *(const bf16x8*)((const char*)Bsm + row * 128 + (bcol ^ ((row & 7) << 4)));
            }
#pragma unroll
            for (int mi = 0; mi < 4; ++mi)
#pragma unroll
                for (int ni = 0; ni < 4; ++ni)
                    acc[mi][ni] = __builtin_amdgcn_mfma_f32_16x16x32_bf16(af[mi], bfr[ni], acc[mi][ni], 0, 0, 0);
        }
        __syncthreads();
    }

    const int cl = lane & 15;           // n offset within fragment
    const int rg = (lane >> 4) << 2;    // m base within fragment

    if constexpr (EPI == 0) {           // GI = TE@Wih.T + bih  (fp32 [n][3072])
#pragma unroll
        for (int mi = 0; mi < 4; ++mi) {
            int m0 = mt * 128 + wm * 64 + mi * 16 + rg;
            float4 bias = *(const float4*)(p0 + m0);
#pragma unroll
            for (int ni = 0; ni < 4; ++ni) {
                int n = nt * 128 + wn * 64 + ni * 16 + cl;
                float4 v;
                v.x = acc[mi][ni][0] + bias.x; v.y = acc[mi][ni][1] + bias.y;
                v.z = acc[mi][ni][2] + bias.z; v.w = acc[mi][ni][3] + bias.w;
                *(float4*)(q0 + (size_t)n * 3072 + m0) = v;
            }
        }
    }
    if constexpr (EPI == 1) {           // maxout -> BL bf16 [n][512]
#pragma unroll
        for (int mi = 0; mi < 4; ++mi) {
            int m0 = mt * 128 + wm * 64 + mi * 16 + rg;
            float4 eb4 = *(const float4*)(p1 + m0);
#pragma unroll
            for (int ni = 0; ni < 4; ++ni) {
                int n = nt * 128 + wn * 64 + ni * 16 + cl;
                int b = n >> 6;
                float v0 = acc[mi][ni][0] + p0[b * 1024 + m0 + 0] + eb4.x;
                float v1 = acc[mi][ni][1] + p0[b * 1024 + m0 + 1] + eb4.y;
                float v2 = acc[mi][ni][2] + p0[b * 1024 + m0 + 2] + eb4.z;
                float v3 = acc[mi][ni][3] + p0[b * 1024 + m0 + 3] + eb4.w;
                unsigned pk = f2bf(fmaxf(v0, v1)) | ((unsigned)f2bf(fmaxf(v2, v3)) << 16);
                *(unsigned*)(q1 + (size_t)n * 512 + (m0 >> 1)) = pk;
            }
        }
    }
    if constexpr (EPI == 3) {           // logits -> Lb bf16 [n][VOCP] + partial max/sumexp
        __shared__ float redm[2][128];
        __shared__ float reds[2][128];
#pragma unroll
        for (int mi = 0; mi < 4; ++mi) {
            int v0 = mt * 128 + wm * 64 + mi * 16 + rg;
#pragma unroll
            for (int ni = 0; ni < 4; ++ni) {
                int n = nt * 128 + wn * 64 + ni * 16 + cl;
                unsigned lo = f2bf(acc[mi][ni][0]) | ((unsigned)f2bf(acc[mi][ni][1]) << 16);
                unsigned hi = f2bf(acc[mi][ni][2]) | ((unsigned)f2bf(acc[mi][ni][3]) << 16);
                *(uint2*)(q1 + (size_t)n * VOCP + v0) = make_uint2(lo, hi);
            }
        }
#pragma unroll
        for (int ni = 0; ni < 4; ++ni) {
            float lm = -1e30f;
#pragma unroll
            for (int mi = 0; mi < 4; ++mi) {
                int v0 = mt * 128 + wm * 64 + mi * 16 + rg;
#pragma unroll
                for (int r = 0; r < 4; ++r)
                    if (v0 + r < VOC) lm = fmaxf(lm, acc[mi][ni][r]);
            }
            lm = fmaxf(lm, __shfl_xor(lm, 16));
            lm = fmaxf(lm, __shfl_xor(lm, 32));
            float s = 0.0f;
#pragma unroll
            for (int mi = 0; mi < 4; ++mi) {
                int v0 = mt * 128 + wm * 64 + mi * 16 + rg;
#pragma unroll
                for (int r = 0; r < 4; ++r)
                    if (v0 + r < VOC) s += expf(acc[mi][ni][r] - lm);
            }
            s += __shfl_xor(s, 16);
            s += __shfl_xor(s, 32);
            if (lane < 16) {
                redm[wm][wn * 64 + ni * 16 + lane] = lm;
                reds[wm][wn * 64 + ni * 16 + lane] = s;
            }
        }
        __syncthreads();
        if (tid < 128) {
            float m0_ = redm[0][tid], m1_ = redm[1][tid];
            float m = fmaxf(m0_, m1_);
            float s = reds[0][tid] * expf(m0_ - m) + reds[1][tid] * expf(m1_ - m);
            int n = nt * 128 + tid;
            q0[(size_t)n * NTMP + mt] = m;
            q3[(size_t)n * NTMP + mt] = s;
        }
    }
}

// ================================================= 256x256 8-phase gate GEMM, minimal barriers
// (r11-validated, SOUND ledger: every cross-wave LDS read happens after the publishing
// barrier that follows all waves' counted vmcnt waits; no cross-barrier pre-issue).
__global__ __launch_bounds__(512, 1) void gemm_gate8(
    const u16* __restrict__ A,      // A34 [VOCP2][1536]
    const u16* __restrict__ B,      // BG  [2048][1536]
    const float* __restrict__ gc2,  // [32][VOCP2]
    unsigned char* __restrict__ g8) // [2048][VOCP2]
{
    __shared__ __align__(16) char smem[131072];
    const int tid = threadIdx.x;
    const int lane = tid & 63;
    const int w = tid >> 6;
    const int wm = w >> 2;          // 0..1: M half
    const int wn = w & 3;           // 0..3: N quarter
    const int lrow = lane & 15;
    const int g = lane >> 4;

    // XCD-chunked bijective block swizzle: 1568 = 8 * 196
    int bid = blockIdx.x;
    int wg = (bid & 7) * 196 + (bid >> 3);
    int mt = wg >> 3;               // 0..195
    int nt = wg & 7;                // 0..7
    const size_t arow0 = (size_t)mt * 256;
    const size_t brow0 = (size_t)nt * 256;

    auto stageA = [&](int T, int h) {
        char* dst = smem + (T & 1) * 65536 + h * 16384;
        const u16* src = A + (arow0 + h * 128) * 1536 + T * 64;
#pragma unroll
        for (int q = 0; q < 2; ++q) {
            int flat = q * 512 + tid;
            int r = flat >> 3, s = flat & 7;
            int ss = s ^ (r & 7);
            gload_lds16(src + (size_t)r * 1536 + ss * 8, dst + flat * 16);
        }
    };
    auto stageB = [&](int T, int h) {
        char* dst = smem + (T & 1) * 65536 + 32768 + h * 16384;
        const u16* src = B + (brow0 + h * 128) * 1536 + T * 64;
#pragma unroll
        for (int q = 0; q < 2; ++q) {
            int flat = q * 512 + tid;
            int r = flat >> 3, s = flat & 7;
            int ss = s ^ (r & 7);
            gload_lds16(src + (size_t)r * 1536 + ss * 8, dst + flat * 16);
        }
    };

    f32x4 acc[8][4];
#pragma unroll
    for (int i = 0; i < 8; ++i)
#pragma unroll
        for (int j = 0; j < 4; ++j) acc[i][j] = (f32x4){0.f, 0.f, 0.f, 0.f};

    bf16x8 bf[4][2];
    auto loadB_ = [&](int d) {
        char* Bb = smem + d * 65536 + 32768 + (wn >> 1) * 16384;
#pragma unroll
        for (int ni = 0; ni < 4; ++ni) {
            int r = (wn & 1) * 64 + ni * 16 + lrow;
#pragma unroll
            for (int kk = 0; kk < 2; ++kk)
                bf[ni][kk] = *(const bf16x8*)(Bb + r * 128 + ((kk * 64 + g * 16) ^ ((r & 7) << 4)));
        }
    };

#define GPH2(D, Q, LB, STG)                                                           \
    {                                                                                 \
        STG;                                                                          \
        if (LB) loadB_(D);                                                            \
        bf16x8 af[2][2];                                                              \
        char* Ab = smem + (D) * 65536 + wm * 16384;                                   \
        _Pragma("unroll") for (int mi = 0; mi < 2; ++mi) {                            \
            int r = ((Q) * 2 + mi) * 16 + lrow;                                       \
            _Pragma("unroll") for (int kk = 0; kk < 2; ++kk)                          \
                af[mi][kk] = *(const bf16x8*)(Ab + r * 128 +                          \
                                ((kk * 64 + g * 16) ^ ((r & 7) << 4)));               \
        }                                                                             \
        asm volatile("s_waitcnt lgkmcnt(0)" ::: "memory");                            \
        __builtin_amdgcn_sched_barrier(0);                                            \
        __builtin_amdgcn_s_setprio(1);                                                \
        _Pragma("unroll") for (int kk = 0; kk < 2; ++kk)                              \
            _Pragma("unroll") for (int mi = 0; mi < 2; ++mi)                          \
                _Pragma("unroll") for (int ni = 0; ni < 4; ++ni)                      \
                    acc[(Q) * 2 + mi][ni] = __builtin_amdgcn_mfma_f32_16x16x32_bf16(  \
                        af[mi][kk], bf[ni][kk], acc[(Q) * 2 + mi][ni], 0, 0, 0);      \
        __builtin_amdgcn_s_setprio(0);                                                \
    }
#define BARR  __builtin_amdgcn_sched_barrier(0); __builtin_amdgcn_s_barrier(); \
              __builtin_amdgcn_sched_barrier(0)
#define VM4 asm volatile("s_waitcnt vmcnt(4)" ::: "memory"); __builtin_amdgcn_sched_barrier(0)
#define VM0 asm volatile("s_waitcnt vmcnt(0)" ::: "memory"); __builtin_amdgcn_sched_barrier(0)
#define NOPX (void)0

    // prologue: B(0) x2, A(0) x2, B(1) x2  (6 half-tiles, 12 loads)
    stageB(0, 0); stageB(0, 1); stageA(0, 0); stageA(0, 1); stageB(1, 0); stageB(1, 1);
    VM4;                                     // A(0),B(0) landed; B(1) may be in flight
    BARR;

    for (int i = 0; i < 11; ++i) {           // tiles 0..21 computed, staged through 23
        int T0 = 2 * i, T1 = 2 * i + 1;
        GPH2(0, 0, true,  stageA(T1, 0));
        GPH2(0, 1, false, stageA(T1, 1));
        BARR;
        GPH2(0, 2, false, stageB(T0 + 2, 0));
        GPH2(0, 3, false, stageB(T0 + 2, 1));
        VM4; BARR;
        GPH2(1, 0, true,  stageA(T0 + 2, 0));
        GPH2(1, 1, false, stageA(T0 + 2, 1));
        BARR;
        GPH2(1, 2, false, stageB(T1 + 2, 0));
        GPH2(1, 3, false, stageB(T1 + 2, 1));
        VM4; BARR;
    }
    // peeled last iteration: T0=22, T1=23 (A(23) staged here; B(23) staged in i=10)
    GPH2(0, 0, true,  stageA(23, 0));
    GPH2(0, 1, false, stageA(23, 1));
    BARR;
    GPH2(0, 2, false, NOPX);
    GPH2(0, 3, false, NOPX);
    VM0; BARR;
    GPH2(1, 0, true,  NOPX);
    GPH2(1, 1, false, NOPX);
    GPH2(1, 2, false, NOPX);
    GPH2(1, 3, false, NOPX);
#undef GPH2
#undef BARR
#undef VM4
#undef VM0
#undef NOPX

    // ---- epilogue: gate = sigmoid(acc + gc), pack 4 x u8
    const int rg = g << 2;
    const int b = nt * 4 + wn;               // uniform per wave
    const float* gcrow = gc2 + (size_t)b * VOCP2;
#pragma unroll
    for (int m = 0; m < 8; ++m) {
        int v0 = mt * 256 + wm * 128 + m * 16 + rg;
        float4 gcv = *(const float4*)(gcrow + v0);
#pragma unroll
        for (int ni = 0; ni < 4; ++ni) {
            int n = nt * 256 + wn * 64 + ni * 16 + lrow;
            unsigned pk = 0;
#pragma unroll
            for (int r = 0; r < 4; ++r) {
                float garg = acc[m][ni][r] + ((const float*)&gcv)[r];
                float gate = 1.0f / (1.0f + expf(-garg));
                pk |= ((unsigned)(int)(gate * 255.0f + 0.5f)) << (8 * r);
            }
            *(unsigned*)(g8 + (size_t)n * VOCP2 + v0) = pk;
        }
    }
}

// ------------------------------------------------- persistent MFMA GRU v5 (r13-validated)
// 64 blocks x 256 threads. A panel (48x1024 bf16 = 96 KB) resident; per step ALL of
// the wave's h staged up front with ONE vmcnt(0) wait. LDS = 160 KiB (full pool).
__global__ __launch_bounds__(256, 1) void k_gru_m5(const u16* __restrict__ WhhB,
                                                   const float* __restrict__ GI,
                                                   const float* __restrict__ bhh,
                                                   const u16* __restrict__ h0b,
                                                   u16* __restrict__ BG,
                                                   unsigned* __restrict__ flags) {
    __shared__ __align__(16) char smem[163840];
    const int tid = threadIdx.x;
    const int lane = tid & 63;
    const int w = tid >> 6;
    const int jb = blockIdx.x;            // 0..63
    const int j0 = jb * 16;
    const int jl = tid & 15, bp = tid >> 4;
    const int je = j0 + jl;
    const float bh0 = bhh[je], bh1 = bhh[1024 + je], bh2 = bhh[2048 + je];
    char* Bbase = smem + 98304 + w * 16384;

#pragma unroll
    for (int it = 0; it < 24; ++it) {
        int flat = (it * 4 + w) * 64 + lane;
        int r = flat >> 7, s = flat & 127;
        int ss = s ^ (r & 7);
        int gr = (r >> 4) * 1024 + j0 + (r & 15);
        gload_lds16(WhhB + (size_t)gr * 1024 + ss * 8, smem + (size_t)flat * 16);
    }

    float hpv[2];
#pragma unroll
    for (int rb = 0; rb < 2; ++rb)
        hpv[rb] = bf2f(h0b[(size_t)(bp * 2 + rb) * 1024 + je]);

    const int lrow = lane & 15;
    const int ksel = lane >> 4;

    for (int t = 0; t < 64; ++t) {
        const u16* hsrc = (t == 0) ? h0b : BG + (size_t)(t - 1) * 1536;
        const size_t hstr = (t == 0) ? 1024 : (size_t)64 * 1536;

        // stage ALL 4 chunks of this wave's h K-range (16 gload_lds)
#pragma unroll
        for (int c = 0; c < 4; ++c) {
            char* dst = Bbase + c * 4096;
            int kq0 = w * 256 + c * 64;
#pragma unroll
            for (int q = 0; q < 4; ++q) {
                int flat = q * 64 + lane;
                int r = flat >> 3, s = flat & 7;
                int ss = s ^ (r & 7);
                gload_lds16x<0x11>(hsrc + (size_t)r * hstr + kq0 + ss * 8,
                                   dst + (size_t)flat * 16);
            }
        }
        float gi0[2], gi1[2], gi2[2];
#pragma unroll
        for (int rb = 0; rb < 2; ++rb) {
            const float* gp = GI + ((size_t)((bp * 2 + rb) * 64 + t)) * 3072 + je;
            gi0[rb] = gp[0]; gi1[rb] = gp[1024]; gi2[rb] = gp[2048];
        }
        if (t == 0) {
            __syncthreads();
        } else {
            asm volatile("s_waitcnt vmcnt(0)" ::: "memory");
        }
        __builtin_amdgcn_sched_barrier(0);

        f32x4 acc[3][2];
#pragma unroll
        for (int mi = 0; mi < 3; ++mi)
#pragma unroll
            for (int ni = 0; ni < 2; ++ni) acc[mi][ni] = (f32x4){0.f, 0.f, 0.f, 0.f};

#pragma unroll
        for (int c = 0; c < 4; ++c) {
            char* Bb = Bbase + c * 4096;
#pragma unroll
            for (int ks = 0; ks < 2; ++ks) {
                int kb = ks * 64 + ksel * 16;
                bf16x8 bfr[2];
#pragma unroll
                for (int ni = 0; ni < 2; ++ni) {
                    int br = ni * 16 + lrow;
                    bfr[ni] = *(const bf16x8*)(Bb + br * 128 + (kb ^ ((br & 7) << 4)));
                }
                int kA = w * 512 + c * 128 + kb;
#pragma unroll
                for (int mi = 0; mi < 3; ++mi) {
                    int ar = mi * 16 + lrow;
                    bf16x8 af = *(const bf16x8*)(smem + ar * 2048 + (kA ^ ((ar & 7) << 4)));
#pragma unroll
                    for (int ni = 0; ni < 2; ++ni)
                        acc[mi][ni] = __builtin_amdgcn_mfma_f32_16x16x32_bf16(af, bfr[ni], acc[mi][ni], 0, 0, 0);
                }
            }
        }

        float (*epiw)[33] = (float(*)[33])Bbase;
        asm volatile("s_waitcnt lgkmcnt(0)" ::: "memory");
        __builtin_amdgcn_sched_barrier(0);
        {
            const int rg = (lane >> 4) << 2;
#pragma unroll
            for (int mi = 0; mi < 3; ++mi)
#pragma unroll
                for (int ni = 0; ni < 2; ++ni) {
                    int m0 = mi * 16 + rg;
                    int cb = ni * 16 + lrow;
#pragma unroll
                    for (int r = 0; r < 4; ++r) epiw[m0 + r][cb] = acc[mi][ni][r];
                }
        }
        asm volatile("s_waitcnt lgkmcnt(0)" ::: "memory");
        __builtin_amdgcn_s_barrier();

#pragma unroll
        for (int rb = 0; rb < 2; ++rb) {
            int b = bp * 2 + rb;
            float s0 = 0.f, s1 = 0.f, s2 = 0.f;
#pragma unroll
            for (int ww = 0; ww < 4; ++ww) {
                float (*ep)[33] = (float(*)[33])(smem + 98304 + ww * 16384);
                s0 += ep[jl][b]; s1 += ep[16 + jl][b]; s2 += ep[32 + jl][b];
            }
            float rr = sigmoidf_(gi0[rb] + s0 + bh0);
            float zz = sigmoidf_(gi1[rb] + s1 + bh1);
            float nn = tanhf(gi2[rb] + rr * (s2 + bh2));
            float hnew = (1.0f - zz) * nn + zz * hpv[rb];
            hpv[rb] = hnew;
            store_u16_sc(BG + ((size_t)(b * 64 + t)) * 1536 + je, f2bf(hnew));
        }

        if (t < 63) {
            asm volatile("s_waitcnt vmcnt(0)" ::: "memory");
            __syncthreads();
            if (tid == 0)
                __hip_atomic_store(&flags[jb], (unsigned)(t + 1),
                                   __ATOMIC_RELAXED, __HIP_MEMORY_SCOPE_AGENT);
            unsigned tgt = (unsigned)(t + 1);
            while (true) {
                unsigned v = __hip_atomic_load(&flags[lane],
                                               __ATOMIC_RELAXED, __HIP_MEMORY_SCOPE_AGENT);
                if (__all(v >= tgt)) break;
                __builtin_amdgcn_s_sleep(1);
            }
            __builtin_amdgcn_sched_barrier(0);
        }
    }
}

// ------------------------------------------------- per-row lse from partials (NTM tiles)
__global__ __launch_bounds__(256) void k_lse(const float* __restrict__ pmax,
                                             const float* __restrict__ psum,
                                             float* __restrict__ lse) {
    int n = blockIdx.x;
    int t = threadIdx.x;
    __shared__ float sm[256];
    const float* pm = pmax + (size_t)n * NTMP;
    const float* ps = psum + (size_t)n * NTMP;
    float m = -1e30f;
    for (int p = t; p < NTM; p += 256) m = fmaxf(m, pm[p]);
    sm[t] = m;
    __syncthreads();
    for (int s = 128; s > 0; s >>= 1) { if (t < s) sm[t] = fmaxf(sm[t], sm[t + s]); __syncthreads(); }
    m = sm[0];
    __syncthreads();
    float s = 0.0f;
    for (int p = t; p < NTM; p += 256) s += ps[p] * expf(pm[p] - m);
    sm[t] = s;
    __syncthreads();
    for (int r = 128; r > 0; r >>= 1) { if (t < r) sm[t] += sm[t + r]; __syncthreads(); }
    if (t == 0) lse[n] = m + logf(sm[0]);
}

// ------------------------------------------------- final combine (fully coalesced)
__global__ __launch_bounds__(256) void k_final(const u16* __restrict__ Lb,
                                               const unsigned char* __restrict__ g8,
                                               const float* __restrict__ lse,
                                               const float* __restrict__ ks,
                                               const float* __restrict__ lsek,
                                               float* __restrict__ out) {
    int n = blockIdx.y;
    int b = n >> 6;
    float lsen = lse[n], lkb = lsek[b];
    int base = blockIdx.x * 2048;
#pragma unroll
    for (int i = 0; i < 8; ++i) {
        int v = base + i * 256 + threadIdx.x;
        if (v < VOC) {
            float L = bf2f(Lb[(size_t)n * VOCP + v]);
            float g = g8[(size_t)n * VOCP2 + v] * (1.0f / 255.0f);
            float kp = ((v >= 10 && v < 10 + KSN) ? ks[(size_t)b * KSN + (v - 10)] : 0.0f) - lkb;
            out[(size_t)n * VOC + v] = g * (L - lsen) + (1.0f - g) * kp;
        }
    }
}

// ---------------------------------------------------------------- launch
extern "C" void kernel_launch(void* const* d_in, const int* in_sizes, int n_in,
                              void* d_out, int out_size, void* d_ws, size_t ws_size,
                              hipStream_t stream) {
    const float* ses    = (const float*)d_in[0];
    const float* know   = (const float*)d_in[1];
    const int*   target = (const int*)d_in[2];
    const float* embed  = (const float*)d_in[3];
    const float* Wih    = (const float*)d_in[4];
    const float* Whh    = (const float*)d_in[5];
    const float* bih    = (const float*)d_in[6];
    const float* bhh    = (const float*)d_in[7];
    const float* sdw    = (const float*)d_in[8];
    const float* sdb    = (const float*)d_in[9];
    const float* dw     = (const float*)d_in[10];
    const float* siw    = (const float*)d_in[11];
    const float* ew     = (const float*)d_in[12];
    const float* eb     = (const float*)d_in[13];
    const float* W1     = (const float*)d_in[14];
    const float* W2     = (const float*)d_in[15];
    const float* W3     = (const float*)d_in[16];
    const float* W4     = (const float*)d_in[17];
    const float* kvw    = (const float*)d_in[18];

    char* ws = (char*)d_ws;
    size_t o = 0;
    auto alloc = [&](size_t bytes) { char* r = ws + o; o += (bytes + 255) & ~(size_t)255; return r; };
    u16*   Aemb  = (u16*)  alloc((size_t)VOCP * 512 * 2);
    u16*   A34   = (u16*)  alloc((size_t)VOCP2 * 1536 * 2);
    u16*   Adwew = (u16*)  alloc((size_t)1024 * 1536 * 2);
    u16*   Wihb  = (u16*)  alloc((size_t)3072 * 512 * 2);
    u16*   WhhB  = (u16*)  alloc((size_t)3072 * 1024 * 2);
    u16*   h0b   = (u16*)  alloc((size_t)32 * 1024 * 2);
    u16*   BG    = (u16*)  alloc((size_t)2048 * 1536 * 2);
    u16*   BL    = (u16*)  alloc((size_t)2048 * 512 * 2);
    float* GI    = (float*)alloc((size_t)2048 * 3072 * 4);
    float* h0    = (float*)alloc((size_t)32 * 1024 * 4);
    float* sesinf= (float*)alloc((size_t)32 * 1024 * 4);
    float* gc    = (float*)alloc((size_t)32 * VOCP2 * 4);
    float* ksb   = (float*)alloc((size_t)32 * KSN * 4);
    float* lsek  = (float*)alloc(256);
    float* lse   = (float*)alloc((size_t)2048 * 4);
    unsigned* flags = (unsigned*)alloc(256);
    float* pmax  = (float*)alloc((size_t)2048 * NTMP * 4);
    float* psum  = (float*)alloc((size_t)2048 * NTMP * 4);
    unsigned char* g8 = (unsigned char*)alloc((size_t)2048 * VOCP2);
    u16*   Lb    = (u16*)  alloc((size_t)2048 * VOCP * 2);
    u16*   Bsk   = (u16*)  alloc((size_t)128 * 2048 * 2);
    float* out = (float*)d_out;

    hipMemsetAsync(flags, 0, 256, stream);

    // weight conversions (W1/W2/kvw consumed fp32 by k_sk32)
    k_cvt<<<dim3(VOC, 1), 256, 0, stream>>>(embed, Aemb, 512, 512, 512);
    k_cvt<<<dim3(VOC, 1), 256, 0, stream>>>(W3, A34, 1024, 1024, 1536);
    k_cvt<<<dim3(VOC, 1), 256, 0, stream>>>(W4, A34 + 1024, 512, 512, 1536);
    k_pad0<<<dim3(VOCP2 - VOC), 256, 0, stream>>>(Aemb, A34);
    k_cvt<<<dim3(1024, 1), 256, 0, stream>>>(dw, Adwew, 1024, 1024, 1536);
    k_cvt<<<dim3(1024, 1), 256, 0, stream>>>(ew, Adwew + 1024, 512, 512, 1536);
    k_cvt<<<dim3(3072, 1), 256, 0, stream>>>(Wih, Wihb, 512, 512, 512);
    k_cvt<<<dim3(3072, 1), 256, 0, stream>>>(Whh, WhhB, 1024, 1024, 1024);
    k_bsk<<<dim3(128), 256, 0, stream>>>(ses, know, Bsk);

    k_gather<<<dim3(2048), 128, 0, stream>>>(embed, target, BG);
    k_h0_sesinf<<<dim3(32), 256, 0, stream>>>(ses, sdw, sdb, siw, h0, sesinf);
    k_cvt<<<dim3(32, 1), 256, 0, stream>>>(h0, h0b, 1024, 1024, 1024);

    // gc = [ses|know]·[W1|W2]^T  (fp32-A skinny MFMA, VOCP2 stride)
    k_sk32<0><<<dim3(VOCP2 / 64), 128, 0, stream>>>(W1, W2, Bsk, gc);
    // ks = know·kvw^T
    k_sk32<1><<<dim3((KSN + 63) / 64), 128, 0, stream>>>(kvw, nullptr, Bsk, ksb);
    k_lseknow<<<dim3(32), 256, 0, stream>>>(ksb, lsek);

    // GI = TE @ Wih.T + bih
    gemm_bt<0><<<dim3(16, 24), 256, 0, stream>>>(Wihb, 512, BG + 1024, 1536, 512,
                                                 bih, nullptr, GI, nullptr, nullptr);
    // GRU recurrence: persistent kernel, single-wait staging, 160 KiB LDS
    k_gru_m5<<<dim3(64), 256, 0, stream>>>(WhhB, GI, bhh, h0b, BG, flags);
    // MX (maxout) -> BL
    gemm_bt<1><<<dim3(16, 8), 256, 0, stream>>>(Adwew, 1536, BG, 1536, 1536,
                                                sesinf, eb, nullptr, BL, nullptr);
    // gate GEMM -> g8  (256-tile, minimal-barrier 8-phase, sound ledger)
    gemm_gate8<<<dim3(1568), 512, 0, stream>>>(A34, BG, gc, g8);
    // logit GEMM -> Lb + partials (128-tile, Lb stride VOCP)
    gemm_bt<3><<<dim3(16, NTM), 256, 0, stream>>>(Aemb, 512, BL, 512, 512,
                                                  nullptr, nullptr, pmax, Lb, psum);
    k_lse<<<dim3(2048), 256, 0, stream>>>(pmax, psum, lse);
    k_final<<<dim3(25, 2048), 256, 0, stream>>>(Lb, g8, lse, ksb, lsek, out);
}

// Round 16
// 1528.535 us; speedup vs baseline: 1.0436x; 1.0398x over previous
//
#include <hip/hip_runtime.h>

// Problem dims
constexpr int VOC  = 50005;
constexpr int VOCP = 50048;   // 391*128, padded vocab (128-tile GEMMs)
constexpr int VOCP2= 50176;   // 196*256, padded vocab (256-tile GEMM)
constexpr int NTM  = 391;     // vocab tiles (128) for logit GEMM
constexpr int NTMP = 400;     // padded partial stride
constexpr int KSN  = 8784;    // KNOW-1
constexpr float NPAD = 41221.0f;

typedef unsigned short u16;
typedef __attribute__((ext_vector_type(4))) float f32x4;
typedef __attribute__((ext_vector_type(8))) short bf16x8;

__device__ __forceinline__ float dot4(float4 a, float4 b) {
    return a.x*b.x + a.y*b.y + a.z*b.z + a.w*b.w;
}
__device__ __forceinline__ float sigmoidf_(float x) { return 1.0f / (1.0f + expf(-x)); }
__device__ __forceinline__ u16 f2bf(float f) {
    unsigned x = __float_as_uint(f);
    return (u16)((x + 0x7FFFu + ((x >> 16) & 1u)) >> 16);
}
__device__ __forceinline__ float bf2f(u16 u) { return __uint_as_float(((unsigned)u) << 16); }
__device__ __forceinline__ bf16x8 pack8(float4 lo, float4 hi) {
    union { bf16x8 v; unsigned u[4]; } r;
    r.u[0] = f2bf(lo.x) | ((unsigned)f2bf(lo.y) << 16);
    r.u[1] = f2bf(lo.z) | ((unsigned)f2bf(lo.w) << 16);
    r.u[2] = f2bf(hi.x) | ((unsigned)f2bf(hi.y) << 16);
    r.u[3] = f2bf(hi.z) | ((unsigned)f2bf(hi.w) << 16);
    return r.v;
}
template<int AUX>
__device__ __forceinline__ void gload_lds16x(const void* g, void* l) {
    __builtin_amdgcn_global_load_lds((const __attribute__((address_space(1))) unsigned int*)g,
                                     (__attribute__((address_space(3))) unsigned int*)l, 16, 0, AUX);
}
__device__ __forceinline__ void gload_lds16(const void* g, void* l) { gload_lds16x<0>(g, l); }
// device-coherent u16 store (write-through to coherence point, cross-XCD visible)
__device__ __forceinline__ void store_u16_sc(u16* p, u16 v) {
    asm volatile("global_store_short %0, %1, off sc0 sc1" :: "v"(p), "v"((unsigned)v) : "memory");
}
// cvt one float4 -> 4 bf16 packed store
__device__ __forceinline__ void cvt4(const float* src, u16* dst) {
    float4 v = *(const float4*)src;
    unsigned lo = f2bf(v.x) | ((unsigned)f2bf(v.y) << 16);
    unsigned hi = f2bf(v.z) | ((unsigned)f2bf(v.w) << 16);
    *(uint2*)dst = make_uint2(lo, hi);
}

// ---------------------------------------------------------------- cvt fp32 -> bf16 (strided)
__global__ __launch_bounds__(256) void k_cvt(const float* __restrict__ src, u16* __restrict__ dst,
                                             int ncols, int sld, int dld) {
    int row = blockIdx.x;
    int c = (blockIdx.y * 256 + threadIdx.x) * 4;
    if (c >= ncols) return;
    cvt4(src + (size_t)row * sld + c, dst + (size_t)row * dld + c);
}

// build Bsk [128][2048] bf16: rows 0..31 = [ses|know], rows 32..127 = 0
__global__ __launch_bounds__(256) void k_bsk(const float* __restrict__ ses,
                                             const float* __restrict__ know,
                                             u16* __restrict__ Bsk) {
    int row = blockIdx.x;
    for (int c0 = threadIdx.x * 4; c0 < 2048; c0 += 1024) {
        uint2 val = make_uint2(0, 0);
        if (row < 32) {
            const float* srcp = (c0 < 1024) ? ses + (size_t)row * 1024 + c0
                                            : know + (size_t)row * 1024 + (c0 - 1024);
            float4 v = *(const float4*)srcp;
            val = make_uint2(f2bf(v.x) | ((unsigned)f2bf(v.y) << 16),
                             f2bf(v.z) | ((unsigned)f2bf(v.w) << 16));
        }
        *(uint2*)(Bsk + (size_t)row * 2048 + c0) = val;
    }
}

// ---------------------------------------------------------------- gather target embeddings -> BG[:,1024:1536] bf16
__global__ __launch_bounds__(128) void k_gather(const float* __restrict__ embed,
                                                const int* __restrict__ target,
                                                u16* __restrict__ BG) {
    int n = blockIdx.x;
    int row = target[n];
    int c = threadIdx.x * 4;
    cvt4(embed + (size_t)row * 512 + c, BG + (size_t)n * 1536 + 1024 + c);
}

// ------------------------------------------------- h0 + ses_inf_vec (fp32, small)
__global__ __launch_bounds__(256) void k_h0_sesinf(const float* __restrict__ ses,
                                                   const float* __restrict__ sdw,
                                                   const float* __restrict__ sdb,
                                                   const float* __restrict__ siw,
                                                   float* __restrict__ h0,
                                                   float* __restrict__ sesinf) {
    int g = blockIdx.x * 256 + threadIdx.x;
    int b = g & 31;
    int jg = g >> 5;
    int j0 = jg * 4;
    const float4* s4 = (const float4*)(ses + (size_t)b * 1024);
    const float4* wa[4];
    const float4* wc[4];
#pragma unroll
    for (int r = 0; r < 4; ++r) {
        wa[r] = (const float4*)(sdw + (size_t)(j0 + r) * 1024);
        wc[r] = (const float4*)(siw + (size_t)(j0 + r) * 1024);
    }
    float a[4] = {0, 0, 0, 0}, c[4] = {0, 0, 0, 0};
    for (int kq = 0; kq < 256; ++kq) {
        float4 sv = s4[kq];
#pragma unroll
        for (int r = 0; r < 4; ++r) { a[r] += dot4(sv, wa[r][kq]); c[r] += dot4(sv, wc[r][kq]); }
    }
#pragma unroll
    for (int r = 0; r < 4; ++r) {
        h0[b * 1024 + j0 + r] = tanhf(a[r] + sdb[j0 + r]);
        sesinf[b * 1024 + j0 + r] = c[r];
    }
}

// ------------------------------------------------- lse of padded know scores
__global__ __launch_bounds__(256) void k_lseknow(const float* __restrict__ ks,
                                                 float* __restrict__ lsek) {
    int b = blockIdx.x;
    int t = threadIdx.x;
    __shared__ float sm[256];
    float m = -1e30f;
    for (int j = t; j < KSN; j += 256) m = fmaxf(m, ks[(size_t)b * KSN + j]);
    sm[t] = m;
    __syncthreads();
    for (int s = 128; s > 0; s >>= 1) { if (t < s) sm[t] = fmaxf(sm[t], sm[t + s]); __syncthreads(); }
    m = fmaxf(sm[0], 0.0f);
    __syncthreads();
    float s = 0.0f;
    for (int j = t; j < KSN; j += 256) s += expf(ks[(size_t)b * KSN + j] - m);
    sm[t] = s;
    __syncthreads();
    for (int r = 128; r > 0; r >>= 1) { if (t < r) sm[t] += sm[t + r]; __syncthreads(); }
    if (t == 0) lsek[b] = m + logf(sm[0] + NPAD * expf(0.0f - m));
}

// ================================================= skinny-N=32 fp32-A MFMA GEMM (no cvt pass)
template<int MODE>
__global__ __launch_bounds__(128) void k_sk32(const float* __restrict__ A1,
                                              const float* __restrict__ A2,
                                              const u16* __restrict__ Bsk,
                                              float* __restrict__ outp) {
    const int lane = threadIdx.x & 63;
    const int w = threadIdx.x >> 6;
    const int lrow = lane & 15;
    const int kg = lane >> 4;
    constexpr int K = (MODE == 0) ? 2048 : 1024;
    constexpr int bc0 = (MODE == 0) ? 0 : 1024;
    const int rowmax = (MODE == 0) ? (VOC - 1) : (KSN - 1);
    const int vb = blockIdx.x * 64 + w * 32;
    const int r0 = min(vb + lrow, rowmax);
    const int r1 = min(vb + 16 + lrow, rowmax);
    f32x4 acc[2][2] = {{{0.f,0.f,0.f,0.f},{0.f,0.f,0.f,0.f}},
                       {{0.f,0.f,0.f,0.f},{0.f,0.f,0.f,0.f}}};
    for (int k0 = 0; k0 < K; k0 += 32) {
        int kc = k0 + kg * 8;
        const float* s0;
        const float* s1;
        if (MODE == 0 && k0 >= 1024) {
            s0 = A2 + (size_t)r0 * 1024 + (kc - 1024);
            s1 = A2 + (size_t)r1 * 1024 + (kc - 1024);
        } else {
            s0 = A1 + (size_t)r0 * 1024 + kc;
            s1 = A1 + (size_t)r1 * 1024 + kc;
        }
        bf16x8 af0 = pack8(*(const float4*)s0, *(const float4*)(s0 + 4));
        bf16x8 af1 = pack8(*(const float4*)s1, *(const float4*)(s1 + 4));
        bf16x8 b0 = *(const bf16x8*)(Bsk + (size_t)lrow * 2048 + bc0 + kc);
        bf16x8 b1 = *(const bf16x8*)(Bsk + (size_t)(16 + lrow) * 2048 + bc0 + kc);
        acc[0][0] = __builtin_amdgcn_mfma_f32_16x16x32_bf16(af0, b0, acc[0][0], 0, 0, 0);
        acc[0][1] = __builtin_amdgcn_mfma_f32_16x16x32_bf16(af0, b1, acc[0][1], 0, 0, 0);
        acc[1][0] = __builtin_amdgcn_mfma_f32_16x16x32_bf16(af1, b0, acc[1][0], 0, 0, 0);
        acc[1][1] = __builtin_amdgcn_mfma_f32_16x16x32_bf16(af1, b1, acc[1][1], 0, 0, 0);
    }
    const int rg = kg * 4;
#pragma unroll
    for (int mi = 0; mi < 2; ++mi)
#pragma unroll
        for (int ni = 0; ni < 2; ++ni)
#pragma unroll
            for (int r = 0; r < 4; ++r) {
                int v = vb + mi * 16 + rg + r;
                int b = ni * 16 + lrow;
                if (MODE == 0) outp[(size_t)b * VOCP2 + v] = acc[mi][ni][r];
                else if (v < KSN) outp[(size_t)b * KSN + v] = acc[mi][ni][r];
            }
}

// ================================================= templated bf16 MFMA GEMM 128-tile
// EPI 0: GI (+bias, fp32)  EPI 1: MX maxout  EPI 3: logits+partials (Lb stride VOCP)
template<int EPI>
__global__ __launch_bounds__(256) void gemm_bt(
    const u16* __restrict__ A, int lda,
    const u16* __restrict__ B, int ldb, int K,
    const float* __restrict__ p0, const float* __restrict__ p1,
    float* __restrict__ q0, u16* __restrict__ q1, float* __restrict__ q3)
{
    __shared__ u16 Asm[128 * 64];
    __shared__ u16 Bsm[128 * 64];
    const int tid = threadIdx.x;
    const int lane = tid & 63;
    const int w = tid >> 6;
    const int wm = w >> 1, wn = w & 1;
    const int nt = blockIdx.x, mt = blockIdx.y;

    f32x4 acc[4][4];
#pragma unroll
    for (int i = 0; i < 4; ++i)
#pragma unroll
        for (int j = 0; j < 4; ++j) acc[i][j] = (f32x4){0.f, 0.f, 0.f, 0.f};

    for (int kt = 0; kt < K; kt += 64) {
#pragma unroll
        for (int p = 0; p < 4; ++p) {
            int flat = (w * 4 + p) * 64 + lane;       // 0..1023 16B-slots
            int row = flat >> 3, slot = flat & 7;
            int ss = slot ^ (row & 7);                // inverse-swizzled source slot
            gload_lds16(A + (size_t)(mt * 128 + row) * lda + kt + ss * 8, Asm + flat * 8);
            gload_lds16(B + (size_t)(nt * 128 + row) * ldb + kt + ss * 8, Bsm + flat * 8);
        }
        __syncthreads();
#pragma unroll
        for (int kc = 0; kc < 2; ++kc) {
            bf16x8 af[4], bfr[4];
#pragma unroll
            for (int mi = 0; mi < 4; ++mi) {
                int row = wm * 64 + mi * 16 + (lane & 15);
                int bcol = kc * 64 + ((lane >> 4) << 4);
                af[mi] = *(const bf16x8*)((const char*)Asm + row * 128 + (bcol ^ ((row & 7) << 4)));
            }
#pragma unroll
            for (int ni = 0; ni < 4; ++ni) {
                int row = wn * 64 + ni * 16 + (lane & 15);
                int bcol = kc * 64 + ((lane >> 4) << 4);
                bfr[ni] = *(const bf16x8*)((const char*)Bsm + row * 128 + (bcol ^ ((row & 7) << 4)));
            }
#pragma unroll
            for (int mi = 0; mi < 4; ++mi)
#pragma unroll
                for (int ni = 0; ni < 4; ++ni)
                    acc[mi][ni] = __builtin_amdgcn_mfma_f32_16x16x32_bf16(af[mi], bfr[ni], acc[mi][ni], 0, 0, 0);
        }
        __syncthreads();
    }

    const int cl = lane & 15;           // n offset within fragment
    const int rg = (lane >> 4) << 2;    // m base within fragment

    if constexpr (EPI == 0) {           // GI = TE@Wih.T + bih  (fp32 [n][3072])
#pragma unroll
        for (int mi = 0; mi < 4; ++mi) {
            int m0 = mt * 128 + wm * 64 + mi * 16 + rg;
            float4 bias = *(const float4*)(p0 + m0);
#pragma unroll
            for (int ni = 0; ni < 4; ++ni) {
                int n = nt * 128 + wn * 64 + ni * 16 + cl;
                float4 v;
                v.x = acc[mi][ni][0] + bias.x; v.y = acc[mi][ni][1] + bias.y;
                v.z = acc[mi][ni][2] + bias.z; v.w = acc[mi][ni][3] + bias.w;
                *(float4*)(q0 + (size_t)n * 3072 + m0) = v;
            }
        }
    }
    if constexpr (EPI == 1) {           // maxout -> BL bf16 [n][512]
#pragma unroll
        for (int mi = 0; mi < 4; ++mi) {
            int m0 = mt * 128 + wm * 64 + mi * 16 + rg;
            float4 eb4 = *(const float4*)(p1 + m0);
#pragma unroll
            for (int ni = 0; ni < 4; ++ni) {
                int n = nt * 128 + wn * 64 + ni * 16 + cl;
                int b = n >> 6;
                float v0 = acc[mi][ni][0] + p0[b * 1024 + m0 + 0] + eb4.x;
                float v1 = acc[mi][ni][1] + p0[b * 1024 + m0 + 1] + eb4.y;
                float v2 = acc[mi][ni][2] + p0[b * 1024 + m0 + 2] + eb4.z;
                float v3 = acc[mi][ni][3] + p0[b * 1024 + m0 + 3] + eb4.w;
                unsigned pk = f2bf(fmaxf(v0, v1)) | ((unsigned)f2bf(fmaxf(v2, v3)) << 16);
                *(unsigned*)(q1 + (size_t)n * 512 + (m0 >> 1)) = pk;
            }
        }
    }
    if constexpr (EPI == 3) {           // logits -> Lb bf16 [n][VOCP] + partial max/sumexp
        __shared__ float redm[2][128];
        __shared__ float reds[2][128];
#pragma unroll
        for (int mi = 0; mi < 4; ++mi) {
            int v0 = mt * 128 + wm * 64 + mi * 16 + rg;
#pragma unroll
            for (int ni = 0; ni < 4; ++ni) {
                int n = nt * 128 + wn * 64 + ni * 16 + cl;
                unsigned lo = f2bf(acc[mi][ni][0]) | ((unsigned)f2bf(acc[mi][ni][1]) << 16);
                unsigned hi = f2bf(acc[mi][ni][2]) | ((unsigned)f2bf(acc[mi][ni][3]) << 16);
                *(uint2*)(q1 + (size_t)n * VOCP + v0) = make_uint2(lo, hi);
            }
        }
#pragma unroll
        for (int ni = 0; ni < 4; ++ni) {
            float lm = -1e30f;
#pragma unroll
            for (int mi = 0; mi < 4; ++mi) {
                int v0 = mt * 128 + wm * 64 + mi * 16 + rg;
#pragma unroll
                for (int r = 0; r < 4; ++r)
                    if (v0 + r < VOC) lm = fmaxf(lm, acc[mi][ni][r]);
            }
            lm = fmaxf(lm, __shfl_xor(lm, 16));
            lm = fmaxf(lm, __shfl_xor(lm, 32));
            float s = 0.0f;
#pragma unroll
            for (int mi = 0; mi < 4; ++mi) {
                int v0 = mt * 128 + wm * 64 + mi * 16 + rg;
#pragma unroll
                for (int r = 0; r < 4; ++r)
                    if (v0 + r < VOC) s += expf(acc[mi][ni][r] - lm);
            }
            s += __shfl_xor(s, 16);
            s += __shfl_xor(s, 32);
            if (lane < 16) {
                redm[wm][wn * 64 + ni * 16 + lane] = lm;
                reds[wm][wn * 64 + ni * 16 + lane] = s;
            }
        }
        __syncthreads();
        if (tid < 128) {
            float m0_ = redm[0][tid], m1_ = redm[1][tid];
            float m = fmaxf(m0_, m1_);
            float s = reds[0][tid] * expf(m0_ - m) + reds[1][tid] * expf(m1_ - m);
            int n = nt * 128 + tid;
            q0[(size_t)n * NTMP + mt] = m;
            q3[(size_t)n * NTMP + mt] = s;
        }
    }
}

// ================================================= 256x256 8-phase gate GEMM, minimal barriers
// (r11/r15-validated, sound ledger)
__global__ __launch_bounds__(512, 1) void gemm_gate8(
    const u16* __restrict__ A,      // A34 [VOCP2][1536]
    const u16* __restrict__ B,      // BG  [2048][1536]
    const float* __restrict__ gc2,  // [32][VOCP2]
    unsigned char* __restrict__ g8) // [2048][VOCP2]
{
    __shared__ __align__(16) char smem[131072];
    const int tid = threadIdx.x;
    const int lane = tid & 63;
    const int w = tid >> 6;
    const int wm = w >> 2;          // 0..1: M half
    const int wn = w & 3;           // 0..3: N quarter
    const int lrow = lane & 15;
    const int g = lane >> 4;

    // XCD-chunked bijective block swizzle: 1568 = 8 * 196
    int bid = blockIdx.x;
    int wg = (bid & 7) * 196 + (bid >> 3);
    int mt = wg >> 3;               // 0..195
    int nt = wg & 7;                // 0..7
    const size_t arow0 = (size_t)mt * 256;
    const size_t brow0 = (size_t)nt * 256;

    auto stageA = [&](int T, int h) {
        char* dst = smem + (T & 1) * 65536 + h * 16384;
        const u16* src = A + (arow0 + h * 128) * 1536 + T * 64;
#pragma unroll
        for (int q = 0; q < 2; ++q) {
            int flat = q * 512 + tid;
            int r = flat >> 3, s = flat & 7;
            int ss = s ^ (r & 7);
            gload_lds16(src + (size_t)r * 1536 + ss * 8, dst + flat * 16);
        }
    };
    auto stageB = [&](int T, int h) {
        char* dst = smem + (T & 1) * 65536 + 32768 + h * 16384;
        const u16* src = B + (brow0 + h * 128) * 1536 + T * 64;
#pragma unroll
        for (int q = 0; q < 2; ++q) {
            int flat = q * 512 + tid;
            int r = flat >> 3, s = flat & 7;
            int ss = s ^ (r & 7);
            gload_lds16(src + (size_t)r * 1536 + ss * 8, dst + flat * 16);
        }
    };

    f32x4 acc[8][4];
#pragma unroll
    for (int i = 0; i < 8; ++i)
#pragma unroll
        for (int j = 0; j < 4; ++j) acc[i][j] = (f32x4){0.f, 0.f, 0.f, 0.f};

    bf16x8 bf[4][2];
    auto loadB_ = [&](int d) {
        char* Bb = smem + d * 65536 + 32768 + (wn >> 1) * 16384;
#pragma unroll
        for (int ni = 0; ni < 4; ++ni) {
            int r = (wn & 1) * 64 + ni * 16 + lrow;
#pragma unroll
            for (int kk = 0; kk < 2; ++kk)
                bf[ni][kk] = *(const bf16x8*)(Bb + r * 128 + ((kk * 64 + g * 16) ^ ((r & 7) << 4)));
        }
    };

#define GPH2(D, Q, LB, STG)                                                           \
    {                                                                                 \
        STG;                                                                          \
        if (LB) loadB_(D);                                                            \
        bf16x8 af[2][2];                                                              \
        char* Ab = smem + (D) * 65536 + wm * 16384;                                   \
        _Pragma("unroll") for (int mi = 0; mi < 2; ++mi) {                            \
            int r = ((Q) * 2 + mi) * 16 + lrow;                                       \
            _Pragma("unroll") for (int kk = 0; kk < 2; ++kk)                          \
                af[mi][kk] = *(const bf16x8*)(Ab + r * 128 +                          \
                                ((kk * 64 + g * 16) ^ ((r & 7) << 4)));               \
        }                                                                             \
        asm volatile("s_waitcnt lgkmcnt(0)" ::: "memory");                            \
        __builtin_amdgcn_sched_barrier(0);                                            \
        __builtin_amdgcn_s_setprio(1);                                                \
        _Pragma("unroll") for (int kk = 0; kk < 2; ++kk)                              \
            _Pragma("unroll") for (int mi = 0; mi < 2; ++mi)                          \
                _Pragma("unroll") for (int ni = 0; ni < 4; ++ni)                      \
                    acc[(Q) * 2 + mi][ni] = __builtin_amdgcn_mfma_f32_16x16x32_bf16(  \
                        af[mi][kk], bf[ni][kk], acc[(Q) * 2 + mi][ni], 0, 0, 0);      \
        __builtin_amdgcn_s_setprio(0);                                                \
    }
#define BARR  __builtin_amdgcn_sched_barrier(0); __builtin_amdgcn_s_barrier(); \
              __builtin_amdgcn_sched_barrier(0)
#define VM4 asm volatile("s_waitcnt vmcnt(4)" ::: "memory"); __builtin_amdgcn_sched_barrier(0)
#define VM0 asm volatile("s_waitcnt vmcnt(0)" ::: "memory"); __builtin_amdgcn_sched_barrier(0)
#define NOPX (void)0

    // prologue: B(0) x2, A(0) x2, B(1) x2  (6 half-tiles, 12 loads)
    stageB(0, 0); stageB(0, 1); stageA(0, 0); stageA(0, 1); stageB(1, 0); stageB(1, 1);
    VM4;                                     // A(0),B(0) landed; B(1) may be in flight
    BARR;

    for (int i = 0; i < 11; ++i) {           // tiles 0..21 computed, staged through 23
        int T0 = 2 * i, T1 = 2 * i + 1;
        GPH2(0, 0, true,  stageA(T1, 0));
        GPH2(0, 1, false, stageA(T1, 1));
        BARR;
        GPH2(0, 2, false, stageB(T0 + 2, 0));
        GPH2(0, 3, false, stageB(T0 + 2, 1));
        VM4; BARR;
        GPH2(1, 0, true,  stageA(T0 + 2, 0));
        GPH2(1, 1, false, stageA(T0 + 2, 1));
        BARR;
        GPH2(1, 2, false, stageB(T1 + 2, 0));
        GPH2(1, 3, false, stageB(T1 + 2, 1));
        VM4; BARR;
    }
    // peeled last iteration: T0=22, T1=23 (A(23) staged here; B(23) staged in i=10)
    GPH2(0, 0, true,  stageA(23, 0));
    GPH2(0, 1, false, stageA(23, 1));
    BARR;
    GPH2(0, 2, false, NOPX);
    GPH2(0, 3, false, NOPX);
    VM0; BARR;
    GPH2(1, 0, true,  NOPX);
    GPH2(1, 1, false, NOPX);
    GPH2(1, 2, false, NOPX);
    GPH2(1, 3, false, NOPX);
#undef GPH2
#undef BARR
#undef VM4
#undef VM0
#undef NOPX

    // ---- epilogue: gate = sigmoid(acc + gc), pack 4 x u8
    const int rg = g << 2;
    const int b = nt * 4 + wn;               // uniform per wave
    const float* gcrow = gc2 + (size_t)b * VOCP2;
#pragma unroll
    for (int m = 0; m < 8; ++m) {
        int v0 = mt * 256 + wm * 128 + m * 16 + rg;
        float4 gcv = *(const float4*)(gcrow + v0);
#pragma unroll
        for (int ni = 0; ni < 4; ++ni) {
            int n = nt * 256 + wn * 64 + ni * 16 + lrow;
            unsigned pk = 0;
#pragma unroll
            for (int r = 0; r < 4; ++r) {
                float garg = acc[m][ni][r] + ((const float*)&gcv)[r];
                float gate = 1.0f / (1.0f + expf(-garg));
                pk |= ((unsigned)(int)(gate * 255.0f + 0.5f)) << (8 * r);
            }
            *(unsigned*)(g8 + (size_t)n * VOCP2 + v0) = pk;
        }
    }
}

// ------------------------------------------------- FUSED persistent GRU + helper cvt blocks
// Grid 256 x 256 threads, 1 block/CU (160 KiB LDS keeps all co-resident).
// Blocks 0..63: GRU v5 persistent loop (r13/r15-validated, byte-identical math).
// Blocks 64..255: grid-stride cvt/pad tasks (embed->Aemb, W3/W4->A34, dw/ew->Adwew, pads)
// — fully independent of the GRU; consumers launch after this kernel (stream order).
__global__ __launch_bounds__(256, 1) void k_gru_f(const u16* __restrict__ WhhB,
                                                  const float* __restrict__ GI,
                                                  const float* __restrict__ bhh,
                                                  const u16* __restrict__ h0b,
                                                  u16* __restrict__ BG,
                                                  unsigned* __restrict__ flags,
                                                  const float* __restrict__ embed,
                                                  const float* __restrict__ W3,
                                                  const float* __restrict__ W4,
                                                  const float* __restrict__ dw,
                                                  const float* __restrict__ ew,
                                                  u16* __restrict__ Aemb,
                                                  u16* __restrict__ A34,
                                                  u16* __restrict__ Adwew) {
    __shared__ __align__(16) char smem[163840];
    const int tid = threadIdx.x;

    if (blockIdx.x >= 64) {
        // ---------------- helper path: streaming cvt/pad ----------------
        const long gtid = (long)(blockIdx.x - 64) * 256 + tid;
        const long gstr = 192L * 256;
        // embed -> Aemb (VOC rows x 128 f4)
        for (long i = gtid; i < (long)VOC * 128; i += gstr) {
            int row = (int)(i >> 7), c4 = ((int)i & 127) * 4;
            cvt4(embed + (size_t)row * 512 + c4, Aemb + (size_t)row * 512 + c4);
        }
        // W3 -> A34[:, :1024] (VOC x 256 f4)
        for (long i = gtid; i < (long)VOC * 256; i += gstr) {
            int row = (int)(i >> 8), c4 = ((int)i & 255) * 4;
            cvt4(W3 + (size_t)row * 1024 + c4, A34 + (size_t)row * 1536 + c4);
        }
        // W4 -> A34[:, 1024:1536] (VOC x 128 f4)
        for (long i = gtid; i < (long)VOC * 128; i += gstr) {
            int row = (int)(i >> 7), c4 = ((int)i & 127) * 4;
            cvt4(W4 + (size_t)row * 512 + c4, A34 + (size_t)row * 1536 + 1024 + c4);
        }
        // dw -> Adwew[:, :1024] (1024 x 256 f4)
        for (long i = gtid; i < 1024L * 256; i += gstr) {
            int row = (int)(i >> 8), c4 = ((int)i & 255) * 4;
            cvt4(dw + (size_t)row * 1024 + c4, Adwew + (size_t)row * 1536 + c4);
        }
        // ew -> Adwew[:, 1024:1536] (1024 x 128 f4)
        for (long i = gtid; i < 1024L * 128; i += gstr) {
            int row = (int)(i >> 7), c4 = ((int)i & 127) * 4;
            cvt4(ew + (size_t)row * 512 + c4, Adwew + (size_t)row * 1536 + 1024 + c4);
        }
        // pad A34 rows VOC..VOCP2-1 (u32 zeros)
        for (long i = gtid; i < (long)(VOCP2 - VOC) * 768; i += gstr) {
            int row = VOC + (int)(i / 768), c = (int)(i % 768);
            ((unsigned*)(A34 + (size_t)row * 1536))[c] = 0;
        }
        // pad Aemb rows VOC..VOCP-1
        for (long i = gtid; i < (long)(VOCP - VOC) * 256; i += gstr) {
            int row = VOC + (int)(i >> 8), c = (int)i & 255;
            ((unsigned*)(Aemb + (size_t)row * 512))[c] = 0;
        }
        return;
    }

    // ---------------- GRU path (blocks 0..63), r15-validated ----------------
    const int lane = tid & 63;
    const int w = tid >> 6;
    const int jb = blockIdx.x;            // 0..63
    const int j0 = jb * 16;
    const int jl = tid & 15, bp = tid >> 4;
    const int je = j0 + jl;
    const float bh0 = bhh[je], bh1 = bhh[1024 + je], bh2 = bhh[2048 + je];
    char* Bbase = smem + 98304 + w * 16384;

#pragma unroll
    for (int it = 0; it < 24; ++it) {
        int flat = (it * 4 + w) * 64 + lane;
        int r = flat >> 7, s = flat & 127;
        int ss = s ^ (r & 7);
        int gr = (r >> 4) * 1024 + j0 + (r & 15);
        gload_lds16(WhhB + (size_t)gr * 1024 + ss * 8, smem + (size_t)flat * 16);
    }

    float hpv[2];
#pragma unroll
    for (int rb = 0; rb < 2; ++rb)
        hpv[rb] = bf2f(h0b[(size_t)(bp * 2 + rb) * 1024 + je]);

    const int lrow = lane & 15;
    const int ksel = lane >> 4;

    for (int t = 0; t < 64; ++t) {
        const u16* hsrc = (t == 0) ? h0b : BG + (size_t)(t - 1) * 1536;
        const size_t hstr = (t == 0) ? 1024 : (size_t)64 * 1536;

        // stage ALL 4 chunks of this wave's h K-range (16 gload_lds)
#pragma unroll
        for (int c = 0; c < 4; ++c) {
            char* dst = Bbase + c * 4096;
            int kq0 = w * 256 + c * 64;
#pragma unroll
            for (int q = 0; q < 4; ++q) {
                int flat = q * 64 + lane;
                int r = flat >> 3, s = flat & 7;
                int ss = s ^ (r & 7);
                gload_lds16x<0x11>(hsrc + (size_t)r * hstr + kq0 + ss * 8,
                                   dst + (size_t)flat * 16);
            }
        }
        float gi0[2], gi1[2], gi2[2];
#pragma unroll
        for (int rb = 0; rb < 2; ++rb) {
            const float* gp = GI + ((size_t)((bp * 2 + rb) * 64 + t)) * 3072 + je;
            gi0[rb] = gp[0]; gi1[rb] = gp[1024]; gi2[rb] = gp[2048];
        }
        if (t == 0) {
            __syncthreads();
        } else {
            asm volatile("s_waitcnt vmcnt(0)" ::: "memory");
        }
        __builtin_amdgcn_sched_barrier(0);

        f32x4 acc[3][2];
#pragma unroll
        for (int mi = 0; mi < 3; ++mi)
#pragma unroll
            for (int ni = 0; ni < 2; ++ni) acc[mi][ni] = (f32x4){0.f, 0.f, 0.f, 0.f};

#pragma unroll
        for (int c = 0; c < 4; ++c) {
            char* Bb = Bbase + c * 4096;
#pragma unroll
            for (int ks = 0; ks < 2; ++ks) {
                int kb = ks * 64 + ksel * 16;
                bf16x8 bfr[2];
#pragma unroll
                for (int ni = 0; ni < 2; ++ni) {
                    int br = ni * 16 + lrow;
                    bfr[ni] = *(const bf16x8*)(Bb + br * 128 + (kb ^ ((br & 7) << 4)));
                }
                int kA = w * 512 + c * 128 + kb;
#pragma unroll
                for (int mi = 0; mi < 3; ++mi) {
                    int ar = mi * 16 + lrow;
                    bf16x8 af = *(const bf16x8*)(smem + ar * 2048 + (kA ^ ((ar & 7) << 4)));
#pragma unroll
                    for (int ni = 0; ni < 2; ++ni)
                        acc[mi][ni] = __builtin_amdgcn_mfma_f32_16x16x32_bf16(af, bfr[ni], acc[mi][ni], 0, 0, 0);
                }
            }
        }

        float (*epiw)[33] = (float(*)[33])Bbase;
        asm volatile("s_waitcnt lgkmcnt(0)" ::: "memory");
        __builtin_amdgcn_sched_barrier(0);
        {
            const int rg = (lane >> 4) << 2;
#pragma unroll
            for (int mi = 0; mi < 3; ++mi)
#pragma unroll
                for (int ni = 0; ni < 2; ++ni) {
                    int m0 = mi * 16 + rg;
                    int cb = ni * 16 + lrow;
#pragma unroll
                    for (int r = 0; r < 4; ++r) epiw[m0 + r][cb] = acc[mi][ni][r];
                }
        }
        asm volatile("s_waitcnt lgkmcnt(0)" ::: "memory");
        __builtin_amdgcn_s_barrier();

#pragma unroll
        for (int rb = 0; rb < 2; ++rb) {
            int b = bp * 2 + rb;
            float s0 = 0.f, s1 = 0.f, s2 = 0.f;
#pragma unroll
            for (int ww = 0; ww < 4; ++ww) {
                float (*ep)[33] = (float(*)[33])(smem + 98304 + ww * 16384);
                s0 += ep[jl][b]; s1 += ep[16 + jl][b]; s2 += ep[32 + jl][b];
            }
            float rr = sigmoidf_(gi0[rb] + s0 + bh0);
            float zz = sigmoidf_(gi1[rb] + s1 + bh1);
            float nn = tanhf(gi2[rb] + rr * (s2 + bh2));
            float hnew = (1.0f - zz) * nn + zz * hpv[rb];
            hpv[rb] = hnew;
            store_u16_sc(BG + ((size_t)(b * 64 + t)) * 1536 + je, f2bf(hnew));
        }

        if (t < 63) {
            asm volatile("s_waitcnt vmcnt(0)" ::: "memory");
            __syncthreads();
            if (tid == 0)
                __hip_atomic_store(&flags[jb], (unsigned)(t + 1),
                                   __ATOMIC_RELAXED, __HIP_MEMORY_SCOPE_AGENT);
            unsigned tgt = (unsigned)(t + 1);
            while (true) {
                unsigned v = __hip_atomic_load(&flags[lane],
                                               __ATOMIC_RELAXED, __HIP_MEMORY_SCOPE_AGENT);
                if (__all(v >= tgt)) break;
                __builtin_amdgcn_s_sleep(1);
            }
            __builtin_amdgcn_sched_barrier(0);
        }
    }
}

// ------------------------------------------------- per-row lse from partials (NTM tiles)
__global__ __launch_bounds__(256) void k_lse(const float* __restrict__ pmax,
                                             const float* __restrict__ psum,
                                             float* __restrict__ lse) {
    int n = blockIdx.x;
    int t = threadIdx.x;
    __shared__ float sm[256];
    const float* pm = pmax + (size_t)n * NTMP;
    const float* ps = psum + (size_t)n * NTMP;
    float m = -1e30f;
    for (int p = t; p < NTM; p += 256) m = fmaxf(m, pm[p]);
    sm[t] = m;
    __syncthreads();
    for (int s = 128; s > 0; s >>= 1) { if (t < s) sm[t] = fmaxf(sm[t], sm[t + s]); __syncthreads(); }
    m = sm[0];
    __syncthreads();
    float s = 0.0f;
    for (int p = t; p < NTM; p += 256) s += ps[p] * expf(pm[p] - m);
    sm[t] = s;
    __syncthreads();
    for (int r = 128; r > 0; r >>= 1) { if (t < r) sm[t] += sm[t + r]; __syncthreads(); }
    if (t == 0) lse[n] = m + logf(sm[0]);
}

// ------------------------------------------------- final combine (fully coalesced)
__global__ __launch_bounds__(256) void k_final(const u16* __restrict__ Lb,
                                               const unsigned char* __restrict__ g8,
                                               const float* __restrict__ lse,
                                               const float* __restrict__ ks,
                                               const float* __restrict__ lsek,
                                               float* __restrict__ out) {
    int n = blockIdx.y;
    int b = n >> 6;
    float lsen = lse[n], lkb = lsek[b];
    int base = blockIdx.x * 2048;
#pragma unroll
    for (int i = 0; i < 8; ++i) {
        int v = base + i * 256 + threadIdx.x;
        if (v < VOC) {
            float L = bf2f(Lb[(size_t)n * VOCP + v]);
            float g = g8[(size_t)n * VOCP2 + v] * (1.0f / 255.0f);
            float kp = ((v >= 10 && v < 10 + KSN) ? ks[(size_t)b * KSN + (v - 10)] : 0.0f) - lkb;
            out[(size_t)n * VOC + v] = g * (L - lsen) + (1.0f - g) * kp;
        }
    }
}

// ---------------------------------------------------------------- launch
extern "C" void kernel_launch(void* const* d_in, const int* in_sizes, int n_in,
                              void* d_out, int out_size, void* d_ws, size_t ws_size,
                              hipStream_t stream) {
    const float* ses    = (const float*)d_in[0];
    const float* know   = (const float*)d_in[1];
    const int*   target = (const int*)d_in[2];
    const float* embed  = (const float*)d_in[3];
    const float* Wih    = (const float*)d_in[4];
    const float* Whh    = (const float*)d_in[5];
    const float* bih    = (const float*)d_in[6];
    const float* bhh    = (const float*)d_in[7];
    const float* sdw    = (const float*)d_in[8];
    const float* sdb    = (const float*)d_in[9];
    const float* dw     = (const float*)d_in[10];
    const float* siw    = (const float*)d_in[11];
    const float* ew     = (const float*)d_in[12];
    const float* eb     = (const float*)d_in[13];
    const float* W1     = (const float*)d_in[14];
    const float* W2     = (const float*)d_in[15];
    const float* W3     = (const float*)d_in[16];
    const float* W4     = (const float*)d_in[17];
    const float* kvw    = (const float*)d_in[18];

    char* ws = (char*)d_ws;
    size_t o = 0;
    auto alloc = [&](size_t bytes) { char* r = ws + o; o += (bytes + 255) & ~(size_t)255; return r; };
    u16*   Aemb  = (u16*)  alloc((size_t)VOCP * 512 * 2);
    u16*   A34   = (u16*)  alloc((size_t)VOCP2 * 1536 * 2);
    u16*   Adwew = (u16*)  alloc((size_t)1024 * 1536 * 2);
    u16*   Wihb  = (u16*)  alloc((size_t)3072 * 512 * 2);
    u16*   WhhB  = (u16*)  alloc((size_t)3072 * 1024 * 2);
    u16*   h0b   = (u16*)  alloc((size_t)32 * 1024 * 2);
    u16*   BG    = (u16*)  alloc((size_t)2048 * 1536 * 2);
    u16*   BL    = (u16*)  alloc((size_t)2048 * 512 * 2);
    float* GI    = (float*)alloc((size_t)2048 * 3072 * 4);
    float* h0    = (float*)alloc((size_t)32 * 1024 * 4);
    float* sesinf= (float*)alloc((size_t)32 * 1024 * 4);
    float* gc    = (float*)alloc((size_t)32 * VOCP2 * 4);
    float* ksb   = (float*)alloc((size_t)32 * KSN * 4);
    float* lsek  = (float*)alloc(256);
    float* lse   = (float*)alloc((size_t)2048 * 4);
    unsigned* flags = (unsigned*)alloc(256);
    float* pmax  = (float*)alloc((size_t)2048 * NTMP * 4);
    float* psum  = (float*)alloc((size_t)2048 * NTMP * 4);
    unsigned char* g8 = (unsigned char*)alloc((size_t)2048 * VOCP2);
    u16*   Lb    = (u16*)  alloc((size_t)2048 * VOCP * 2);
    u16*   Bsk   = (u16*)  alloc((size_t)128 * 2048 * 2);
    float* out = (float*)d_out;

    hipMemsetAsync(flags, 0, 256, stream);

    // small preparations (big cvts folded into k_gru_f helper blocks)
    k_cvt<<<dim3(3072, 1), 256, 0, stream>>>(Wih, Wihb, 512, 512, 512);
    k_cvt<<<dim3(3072, 1), 256, 0, stream>>>(Whh, WhhB, 1024, 1024, 1024);
    k_bsk<<<dim3(128), 256, 0, stream>>>(ses, know, Bsk);
    k_gather<<<dim3(2048), 128, 0, stream>>>(embed, target, BG);
    k_h0_sesinf<<<dim3(32), 256, 0, stream>>>(ses, sdw, sdb, siw, h0, sesinf);
    k_cvt<<<dim3(32, 1), 256, 0, stream>>>(h0, h0b, 1024, 1024, 1024);

    // gc = [ses|know]·[W1|W2]^T  (fp32-A skinny MFMA, VOCP2 stride)
    k_sk32<0><<<dim3(VOCP2 / 64), 128, 0, stream>>>(W1, W2, Bsk, gc);
    // ks = know·kvw^T
    k_sk32<1><<<dim3((KSN + 63) / 64), 128, 0, stream>>>(kvw, nullptr, Bsk, ksb);
    k_lseknow<<<dim3(32), 256, 0, stream>>>(ksb, lsek);

    // GI = TE @ Wih.T + bih
    gemm_bt<0><<<dim3(16, 24), 256, 0, stream>>>(Wihb, 512, BG + 1024, 1536, 512,
                                                 bih, nullptr, GI, nullptr, nullptr);
    // FUSED: GRU recurrence (blocks 0..63) + big weight cvts (blocks 64..255)
    k_gru_f<<<dim3(256), 256, 0, stream>>>(WhhB, GI, bhh, h0b, BG, flags,
                                           embed, W3, W4, dw, ew, Aemb, A34, Adwew);
    // MX (maxout) -> BL
    gemm_bt<1><<<dim3(16, 8), 256, 0, stream>>>(Adwew, 1536, BG, 1536, 1536,
                                                sesinf, eb, nullptr, BL, nullptr);
    // gate GEMM -> g8  (256-tile, minimal-barrier 8-phase, sound ledger)
    gemm_gate8<<<dim3(1568), 512, 0, stream>>>(A34, BG, gc, g8);
    // logit GEMM -> Lb + partials (128-tile, Lb stride VOCP)
    gemm_bt<3><<<dim3(16, NTM), 256, 0, stream>>>(Aemb, 512, BL, 512, 512,
                                                  nullptr, nullptr, pmax, Lb, psum);
    k_lse<<<dim3(2048), 256, 0, stream>>>(pmax, psum, lse);
    k_final<<<dim3(25, 2048), 256, 0, stream>>>(Lb, g8, lse, ksb, lsek, out);
}

// Round 17
// 1392.599 us; speedup vs baseline: 1.1455x; 1.0976x over previous
//
#include <hip/hip_runtime.h>

// Problem dims
constexpr int VOC  = 50005;
constexpr int VOCP = 50048;   // 391*128, padded vocab (128-tile GEMMs)
constexpr int VOCP2= 50176;   // 196*256, padded vocab (256-tile GEMM)
constexpr int NTM  = 391;     // vocab tiles (128) for logit GEMM
constexpr int NTMP = 400;     // padded partial stride
constexpr int KSN  = 8784;    // KNOW-1
constexpr float NPAD = 41221.0f;

typedef unsigned short u16;
typedef __attribute__((ext_vector_type(4))) float f32x4;
typedef __attribute__((ext_vector_type(8))) short bf16x8;

__device__ __forceinline__ float dot4(float4 a, float4 b) {
    return a.x*b.x + a.y*b.y + a.z*b.z + a.w*b.w;
}
__device__ __forceinline__ float sigmoidf_(float x) { return 1.0f / (1.0f + expf(-x)); }
__device__ __forceinline__ u16 f2bf(float f) {
    unsigned x = __float_as_uint(f);
    return (u16)((x + 0x7FFFu + ((x >> 16) & 1u)) >> 16);
}
__device__ __forceinline__ float bf2f(u16 u) { return __uint_as_float(((unsigned)u) << 16); }
__device__ __forceinline__ bf16x8 pack8(float4 lo, float4 hi) {
    union { bf16x8 v; unsigned u[4]; } r;
    r.u[0] = f2bf(lo.x) | ((unsigned)f2bf(lo.y) << 16);
    r.u[1] = f2bf(lo.z) | ((unsigned)f2bf(lo.w) << 16);
    r.u[2] = f2bf(hi.x) | ((unsigned)f2bf(hi.y) << 16);
    r.u[3] = f2bf(hi.z) | ((unsigned)f2bf(hi.w) << 16);
    return r.v;
}
template<int AUX>
__device__ __forceinline__ void gload_lds16x(const void* g, void* l) {
    __builtin_amdgcn_global_load_lds((const __attribute__((address_space(1))) unsigned int*)g,
                                     (__attribute__((address_space(3))) unsigned int*)l, 16, 0, AUX);
}
__device__ __forceinline__ void gload_lds16(const void* g, void* l) { gload_lds16x<0>(g, l); }
// device-coherent u16 store (write-through to coherence point, cross-XCD visible)
__device__ __forceinline__ void store_u16_sc(u16* p, u16 v) {
    asm volatile("global_store_short %0, %1, off sc0 sc1" :: "v"(p), "v"((unsigned)v) : "memory");
}
// cvt one float4 -> 4 bf16 packed store
__device__ __forceinline__ void cvt4(const float* src, u16* dst) {
    float4 v = *(const float4*)src;
    unsigned lo = f2bf(v.x) | ((unsigned)f2bf(v.y) << 16);
    unsigned hi = f2bf(v.z) | ((unsigned)f2bf(v.w) << 16);
    *(uint2*)dst = make_uint2(lo, hi);
}
// cvt 64B (4 independent float4 loads -> ILP)
__device__ __forceinline__ void cvt64(const float* src, u16* dst) {
    float4 a = *(const float4*)src;
    float4 b = *(const float4*)(src + 4);
    float4 c = *(const float4*)(src + 8);
    float4 d = *(const float4*)(src + 12);
    uint2 pa = make_uint2(f2bf(a.x) | ((unsigned)f2bf(a.y) << 16), f2bf(a.z) | ((unsigned)f2bf(a.w) << 16));
    uint2 pb = make_uint2(f2bf(b.x) | ((unsigned)f2bf(b.y) << 16), f2bf(b.z) | ((unsigned)f2bf(b.w) << 16));
    uint2 pc = make_uint2(f2bf(c.x) | ((unsigned)f2bf(c.y) << 16), f2bf(c.z) | ((unsigned)f2bf(c.w) << 16));
    uint2 pd = make_uint2(f2bf(d.x) | ((unsigned)f2bf(d.y) << 16), f2bf(d.z) | ((unsigned)f2bf(d.w) << 16));
    *(uint2*)dst = pa; *(uint2*)(dst + 4) = pb; *(uint2*)(dst + 8) = pc; *(uint2*)(dst + 12) = pd;
}

// sk32 task body (identical math to validated k_sk32; 4 waves x 32 rows = 128 rows/task)
template<int MODE>
__device__ void sk32_task(int task, int tid,
                          const float* __restrict__ A1, const float* __restrict__ A2,
                          const u16* __restrict__ Bsk, float* __restrict__ outp) {
    const int lane = tid & 63;
    const int w4 = tid >> 6;              // 0..3
    const int lrow = lane & 15;
    const int kg = lane >> 4;
    constexpr int K = (MODE == 0) ? 2048 : 1024;
    constexpr int bc0 = (MODE == 0) ? 0 : 1024;
    const int rowmax = (MODE == 0) ? (VOC - 1) : (KSN - 1);
    const int vb = task * 128 + w4 * 32;
    const int r0 = min(vb + lrow, rowmax);
    const int r1 = min(vb + 16 + lrow, rowmax);
    f32x4 acc[2][2] = {{{0.f,0.f,0.f,0.f},{0.f,0.f,0.f,0.f}},
                       {{0.f,0.f,0.f,0.f},{0.f,0.f,0.f,0.f}}};
    for (int k0 = 0; k0 < K; k0 += 32) {
        int kc = k0 + kg * 8;
        const float* s0;
        const float* s1;
        if (MODE == 0 && k0 >= 1024) {
            s0 = A2 + (size_t)r0 * 1024 + (kc - 1024);
            s1 = A2 + (size_t)r1 * 1024 + (kc - 1024);
        } else {
            s0 = A1 + (size_t)r0 * 1024 + kc;
            s1 = A1 + (size_t)r1 * 1024 + kc;
        }
        bf16x8 af0 = pack8(*(const float4*)s0, *(const float4*)(s0 + 4));
        bf16x8 af1 = pack8(*(const float4*)s1, *(const float4*)(s1 + 4));
        bf16x8 b0 = *(const bf16x8*)(Bsk + (size_t)lrow * 2048 + bc0 + kc);
        bf16x8 b1 = *(const bf16x8*)(Bsk + (size_t)(16 + lrow) * 2048 + bc0 + kc);
        acc[0][0] = __builtin_amdgcn_mfma_f32_16x16x32_bf16(af0, b0, acc[0][0], 0, 0, 0);
        acc[0][1] = __builtin_amdgcn_mfma_f32_16x16x32_bf16(af0, b1, acc[0][1], 0, 0, 0);
        acc[1][0] = __builtin_amdgcn_mfma_f32_16x16x32_bf16(af1, b0, acc[1][0], 0, 0, 0);
        acc[1][1] = __builtin_amdgcn_mfma_f32_16x16x32_bf16(af1, b1, acc[1][1], 0, 0, 0);
    }
    const int rg = kg * 4;
#pragma unroll
    for (int mi = 0; mi < 2; ++mi)
#pragma unroll
        for (int ni = 0; ni < 2; ++ni)
#pragma unroll
            for (int r = 0; r < 4; ++r) {
                int v = vb + mi * 16 + rg + r;
                int b = ni * 16 + lrow;
                if (MODE == 0) outp[(size_t)b * VOCP2 + v] = acc[mi][ni][r];
                else if (v < KSN) outp[(size_t)b * KSN + v] = acc[mi][ni][r];
            }
}

// ---------------------------------------------------------------- cvt fp32 -> bf16 (strided)
__global__ __launch_bounds__(256) void k_cvt(const float* __restrict__ src, u16* __restrict__ dst,
                                             int ncols, int sld, int dld) {
    int row = blockIdx.x;
    int c = (blockIdx.y * 256 + threadIdx.x) * 4;
    if (c >= ncols) return;
    cvt4(src + (size_t)row * sld + c, dst + (size_t)row * dld + c);
}

// build Bsk [128][2048] bf16: rows 0..31 = [ses|know], rows 32..127 = 0
__global__ __launch_bounds__(256) void k_bsk(const float* __restrict__ ses,
                                             const float* __restrict__ know,
                                             u16* __restrict__ Bsk) {
    int row = blockIdx.x;
    for (int c0 = threadIdx.x * 4; c0 < 2048; c0 += 1024) {
        uint2 val = make_uint2(0, 0);
        if (row < 32) {
            const float* srcp = (c0 < 1024) ? ses + (size_t)row * 1024 + c0
                                            : know + (size_t)row * 1024 + (c0 - 1024);
            float4 v = *(const float4*)srcp;
            val = make_uint2(f2bf(v.x) | ((unsigned)f2bf(v.y) << 16),
                             f2bf(v.z) | ((unsigned)f2bf(v.w) << 16));
        }
        *(uint2*)(Bsk + (size_t)row * 2048 + c0) = val;
    }
}

// ---------------------------------------------------------------- gather target embeddings -> BG[:,1024:1536] bf16
__global__ __launch_bounds__(128) void k_gather(const float* __restrict__ embed,
                                                const int* __restrict__ target,
                                                u16* __restrict__ BG) {
    int n = blockIdx.x;
    int row = target[n];
    int c = threadIdx.x * 4;
    cvt4(embed + (size_t)row * 512 + c, BG + (size_t)n * 1536 + 1024 + c);
}

// ------------------------------------------------- h0 + ses_inf_vec (fp32, small)
__global__ __launch_bounds__(256) void k_h0_sesinf(const float* __restrict__ ses,
                                                   const float* __restrict__ sdw,
                                                   const float* __restrict__ sdb,
                                                   const float* __restrict__ siw,
                                                   float* __restrict__ h0,
                                                   float* __restrict__ sesinf) {
    int g = blockIdx.x * 256 + threadIdx.x;
    int b = g & 31;
    int jg = g >> 5;
    int j0 = jg * 4;
    const float4* s4 = (const float4*)(ses + (size_t)b * 1024);
    const float4* wa[4];
    const float4* wc[4];
#pragma unroll
    for (int r = 0; r < 4; ++r) {
        wa[r] = (const float4*)(sdw + (size_t)(j0 + r) * 1024);
        wc[r] = (const float4*)(siw + (size_t)(j0 + r) * 1024);
    }
    float a[4] = {0, 0, 0, 0}, c[4] = {0, 0, 0, 0};
    for (int kq = 0; kq < 256; ++kq) {
        float4 sv = s4[kq];
#pragma unroll
        for (int r = 0; r < 4; ++r) { a[r] += dot4(sv, wa[r][kq]); c[r] += dot4(sv, wc[r][kq]); }
    }
#pragma unroll
    for (int r = 0; r < 4; ++r) {
        h0[b * 1024 + j0 + r] = tanhf(a[r] + sdb[j0 + r]);
        sesinf[b * 1024 + j0 + r] = c[r];
    }
}

// ------------------------------------------------- lse of padded know scores
__global__ __launch_bounds__(256) void k_lseknow(const float* __restrict__ ks,
                                                 float* __restrict__ lsek) {
    int b = blockIdx.x;
    int t = threadIdx.x;
    __shared__ float sm[256];
    float m = -1e30f;
    for (int j = t; j < KSN; j += 256) m = fmaxf(m, ks[(size_t)b * KSN + j]);
    sm[t] = m;
    __syncthreads();
    for (int s = 128; s > 0; s >>= 1) { if (t < s) sm[t] = fmaxf(sm[t], sm[t + s]); __syncthreads(); }
    m = fmaxf(sm[0], 0.0f);
    __syncthreads();
    float s = 0.0f;
    for (int j = t; j < KSN; j += 256) s += expf(ks[(size_t)b * KSN + j] - m);
    sm[t] = s;
    __syncthreads();
    for (int r = 128; r > 0; r >>= 1) { if (t < r) sm[t] += sm[t + r]; __syncthreads(); }
    if (t == 0) lsek[b] = m + logf(sm[0] + NPAD * expf(0.0f - m));
}

// ================================================= templated bf16 MFMA GEMM 128-tile
// EPI 0: GI (+bias, fp32)  EPI 1: MX maxout  EPI 3: logits+partials (Lb stride VOCP)
template<int EPI>
__global__ __launch_bounds__(256) void gemm_bt(
    const u16* __restrict__ A, int lda,
    const u16* __restrict__ B, int ldb, int K,
    const float* __restrict__ p0, const float* __restrict__ p1,
    float* __restrict__ q0, u16* __restrict__ q1, float* __restrict__ q3)
{
    __shared__ u16 Asm[128 * 64];
    __shared__ u16 Bsm[128 * 64];
    const int tid = threadIdx.x;
    const int lane = tid & 63;
    const int w = tid >> 6;
    const int wm = w >> 1, wn = w & 1;
    const int nt = blockIdx.x, mt = blockIdx.y;

    f32x4 acc[4][4];
#pragma unroll
    for (int i = 0; i < 4; ++i)
#pragma unroll
        for (int j = 0; j < 4; ++j) acc[i][j] = (f32x4){0.f, 0.f, 0.f, 0.f};

    for (int kt = 0; kt < K; kt += 64) {
#pragma unroll
        for (int p = 0; p < 4; ++p) {
            int flat = (w * 4 + p) * 64 + lane;       // 0..1023 16B-slots
            int row = flat >> 3, slot = flat & 7;
            int ss = slot ^ (row & 7);                // inverse-swizzled source slot
            gload_lds16(A + (size_t)(mt * 128 + row) * lda + kt + ss * 8, Asm + flat * 8);
            gload_lds16(B + (size_t)(nt * 128 + row) * ldb + kt + ss * 8, Bsm + flat * 8);
        }
        __syncthreads();
#pragma unroll
        for (int kc = 0; kc < 2; ++kc) {
            bf16x8 af[4], bfr[4];
#pragma unroll
            for (int mi = 0; mi < 4; ++mi) {
                int row = wm * 64 + mi * 16 + (lane & 15);
                int bcol = kc * 64 + ((lane >> 4) << 4);
                af[mi] = *(const bf16x8*)((const char*)Asm + row * 128 + (bcol ^ ((row & 7) << 4)));
            }
#pragma unroll
            for (int ni = 0; ni < 4; ++ni) {
                int row = wn * 64 + ni * 16 + (lane & 15);
                int bcol = kc * 64 + ((lane >> 4) << 4);
                bfr[ni] = *(const bf16x8*)((const char*)Bsm + row * 128 + (bcol ^ ((row & 7) << 4)));
            }
#pragma unroll
            for (int mi = 0; mi < 4; ++mi)
#pragma unroll
                for (int ni = 0; ni < 4; ++ni)
                    acc[mi][ni] = __builtin_amdgcn_mfma_f32_16x16x32_bf16(af[mi], bfr[ni], acc[mi][ni], 0, 0, 0);
        }
        __syncthreads();
    }

    const int cl = lane & 15;           // n offset within fragment
    const int rg = (lane >> 4) << 2;    // m base within fragment

    if constexpr (EPI == 0) {           // GI = TE@Wih.T + bih  (fp32 [n][3072])
#pragma unroll
        for (int mi = 0; mi < 4; ++mi) {
            int m0 = mt * 128 + wm * 64 + mi * 16 + rg;
            float4 bias = *(const float4*)(p0 + m0);
#pragma unroll
            for (int ni = 0; ni < 4; ++ni) {
                int n = nt * 128 + wn * 64 + ni * 16 + cl;
                float4 v;
                v.x = acc[mi][ni][0] + bias.x; v.y = acc[mi][ni][1] + bias.y;
                v.z = acc[mi][ni][2] + bias.z; v.w = acc[mi][ni][3] + bias.w;
                *(float4*)(q0 + (size_t)n * 3072 + m0) = v;
            }
        }
    }
    if constexpr (EPI == 1) {           // maxout -> BL bf16 [n][512]
#pragma unroll
        for (int mi = 0; mi < 4; ++mi) {
            int m0 = mt * 128 + wm * 64 + mi * 16 + rg;
            float4 eb4 = *(const float4*)(p1 + m0);
#pragma unroll
            for (int ni = 0; ni < 4; ++ni) {
                int n = nt * 128 + wn * 64 + ni * 16 + cl;
                int b = n >> 6;
                float v0 = acc[mi][ni][0] + p0[b * 1024 + m0 + 0] + eb4.x;
                float v1 = acc[mi][ni][1] + p0[b * 1024 + m0 + 1] + eb4.y;
                float v2 = acc[mi][ni][2] + p0[b * 1024 + m0 + 2] + eb4.z;
                float v3 = acc[mi][ni][3] + p0[b * 1024 + m0 + 3] + eb4.w;
                unsigned pk = f2bf(fmaxf(v0, v1)) | ((unsigned)f2bf(fmaxf(v2, v3)) << 16);
                *(unsigned*)(q1 + (size_t)n * 512 + (m0 >> 1)) = pk;
            }
        }
    }
    if constexpr (EPI == 3) {           // logits -> Lb bf16 [n][VOCP] + partial max/sumexp
        __shared__ float redm[2][128];
        __shared__ float reds[2][128];
#pragma unroll
        for (int mi = 0; mi < 4; ++mi) {
            int v0 = mt * 128 + wm * 64 + mi * 16 + rg;
#pragma unroll
            for (int ni = 0; ni < 4; ++ni) {
                int n = nt * 128 + wn * 64 + ni * 16 + cl;
                unsigned lo = f2bf(acc[mi][ni][0]) | ((unsigned)f2bf(acc[mi][ni][1]) << 16);
                unsigned hi = f2bf(acc[mi][ni][2]) | ((unsigned)f2bf(acc[mi][ni][3]) << 16);
                *(uint2*)(q1 + (size_t)n * VOCP + v0) = make_uint2(lo, hi);
            }
        }
#pragma unroll
        for (int ni = 0; ni < 4; ++ni) {
            float lm = -1e30f;
#pragma unroll
            for (int mi = 0; mi < 4; ++mi) {
                int v0 = mt * 128 + wm * 64 + mi * 16 + rg;
#pragma unroll
                for (int r = 0; r < 4; ++r)
                    if (v0 + r < VOC) lm = fmaxf(lm, acc[mi][ni][r]);
            }
            lm = fmaxf(lm, __shfl_xor(lm, 16));
            lm = fmaxf(lm, __shfl_xor(lm, 32));
            float s = 0.0f;
#pragma unroll
            for (int mi = 0; mi < 4; ++mi) {
                int v0 = mt * 128 + wm * 64 + mi * 16 + rg;
#pragma unroll
                for (int r = 0; r < 4; ++r)
                    if (v0 + r < VOC) s += expf(acc[mi][ni][r] - lm);
            }
            s += __shfl_xor(s, 16);
            s += __shfl_xor(s, 32);
            if (lane < 16) {
                redm[wm][wn * 64 + ni * 16 + lane] = lm;
                reds[wm][wn * 64 + ni * 16 + lane] = s;
            }
        }
        __syncthreads();
        if (tid < 128) {
            float m0_ = redm[0][tid], m1_ = redm[1][tid];
            float m = fmaxf(m0_, m1_);
            float s = reds[0][tid] * expf(m0_ - m) + reds[1][tid] * expf(m1_ - m);
            int n = nt * 128 + tid;
            q0[(size_t)n * NTMP + mt] = m;
            q3[(size_t)n * NTMP + mt] = s;
        }
    }
}

// ================================================= 256x256 8-phase gate GEMM, minimal barriers
// (r11/r15-validated, sound ledger)
__global__ __launch_bounds__(512, 1) void gemm_gate8(
    const u16* __restrict__ A,      // A34 [VOCP2][1536]
    const u16* __restrict__ B,      // BG  [2048][1536]
    const float* __restrict__ gc2,  // [32][VOCP2]
    unsigned char* __restrict__ g8) // [2048][VOCP2]
{
    __shared__ __align__(16) char smem[131072];
    const int tid = threadIdx.x;
    const int lane = tid & 63;
    const int w = tid >> 6;
    const int wm = w >> 2;          // 0..1: M half
    const int wn = w & 3;           // 0..3: N quarter
    const int lrow = lane & 15;
    const int g = lane >> 4;

    // XCD-chunked bijective block swizzle: 1568 = 8 * 196
    int bid = blockIdx.x;
    int wg = (bid & 7) * 196 + (bid >> 3);
    int mt = wg >> 3;               // 0..195
    int nt = wg & 7;                // 0..7
    const size_t arow0 = (size_t)mt * 256;
    const size_t brow0 = (size_t)nt * 256;

    auto stageA = [&](int T, int h) {
        char* dst = smem + (T & 1) * 65536 + h * 16384;
        const u16* src = A + (arow0 + h * 128) * 1536 + T * 64;
#pragma unroll
        for (int q = 0; q < 2; ++q) {
            int flat = q * 512 + tid;
            int r = flat >> 3, s = flat & 7;
            int ss = s ^ (r & 7);
            gload_lds16(src + (size_t)r * 1536 + ss * 8, dst + flat * 16);
        }
    };
    auto stageB = [&](int T, int h) {
        char* dst = smem + (T & 1) * 65536 + 32768 + h * 16384;
        const u16* src = B + (brow0 + h * 128) * 1536 + T * 64;
#pragma unroll
        for (int q = 0; q < 2; ++q) {
            int flat = q * 512 + tid;
            int r = flat >> 3, s = flat & 7;
            int ss = s ^ (r & 7);
            gload_lds16(src + (size_t)r * 1536 + ss * 8, dst + flat * 16);
        }
    };

    f32x4 acc[8][4];
#pragma unroll
    for (int i = 0; i < 8; ++i)
#pragma unroll
        for (int j = 0; j < 4; ++j) acc[i][j] = (f32x4){0.f, 0.f, 0.f, 0.f};

    bf16x8 bf[4][2];
    auto loadB_ = [&](int d) {
        char* Bb = smem + d * 65536 + 32768 + (wn >> 1) * 16384;
#pragma unroll
        for (int ni = 0; ni < 4; ++ni) {
            int r = (wn & 1) * 64 + ni * 16 + lrow;
#pragma unroll
            for (int kk = 0; kk < 2; ++kk)
                bf[ni][kk] = *(const bf16x8*)(Bb + r * 128 + ((kk * 64 + g * 16) ^ ((r & 7) << 4)));
        }
    };

#define GPH2(D, Q, LB, STG)                                                           \
    {                                                                                 \
        STG;                                                                          \
        if (LB) loadB_(D);                                                            \
        bf16x8 af[2][2];                                                              \
        char* Ab = smem + (D) * 65536 + wm * 16384;                                   \
        _Pragma("unroll") for (int mi = 0; mi < 2; ++mi) {                            \
            int r = ((Q) * 2 + mi) * 16 + lrow;                                       \
            _Pragma("unroll") for (int kk = 0; kk < 2; ++kk)                          \
                af[mi][kk] = *(const bf16x8*)(Ab + r * 128 +                          \
                                ((kk * 64 + g * 16) ^ ((r & 7) << 4)));               \
        }                                                                             \
        asm volatile("s_waitcnt lgkmcnt(0)" ::: "memory");                            \
        __builtin_amdgcn_sched_barrier(0);                                            \
        __builtin_amdgcn_s_setprio(1);                                                \
        _Pragma("unroll") for (int kk = 0; kk < 2; ++kk)                              \
            _Pragma("unroll") for (int mi = 0; mi < 2; ++mi)                          \
                _Pragma("unroll") for (int ni = 0; ni < 4; ++ni)                      \
                    acc[(Q) * 2 + mi][ni] = __builtin_amdgcn_mfma_f32_16x16x32_bf16(  \
                        af[mi][kk], bf[ni][kk], acc[(Q) * 2 + mi][ni], 0, 0, 0);      \
        __builtin_amdgcn_s_setprio(0);                                                \
    }
#define BARR  __builtin_amdgcn_sched_barrier(0); __builtin_amdgcn_s_barrier(); \
              __builtin_amdgcn_sched_barrier(0)
#define VM4 asm volatile("s_waitcnt vmcnt(4)" ::: "memory"); __builtin_amdgcn_sched_barrier(0)
#define VM0 asm volatile("s_waitcnt vmcnt(0)" ::: "memory"); __builtin_amdgcn_sched_barrier(0)
#define NOPX (void)0

    // prologue: B(0) x2, A(0) x2, B(1) x2  (6 half-tiles, 12 loads)
    stageB(0, 0); stageB(0, 1); stageA(0, 0); stageA(0, 1); stageB(1, 0); stageB(1, 1);
    VM4;                                     // A(0),B(0) landed; B(1) may be in flight
    BARR;

    for (int i = 0; i < 11; ++i) {           // tiles 0..21 computed, staged through 23
        int T0 = 2 * i, T1 = 2 * i + 1;
        GPH2(0, 0, true,  stageA(T1, 0));
        GPH2(0, 1, false, stageA(T1, 1));
        BARR;
        GPH2(0, 2, false, stageB(T0 + 2, 0));
        GPH2(0, 3, false, stageB(T0 + 2, 1));
        VM4; BARR;
        GPH2(1, 0, true,  stageA(T0 + 2, 0));
        GPH2(1, 1, false, stageA(T0 + 2, 1));
        BARR;
        GPH2(1, 2, false, stageB(T1 + 2, 0));
        GPH2(1, 3, false, stageB(T1 + 2, 1));
        VM4; BARR;
    }
    // peeled last iteration: T0=22, T1=23 (A(23) staged here; B(23) staged in i=10)
    GPH2(0, 0, true,  stageA(23, 0));
    GPH2(0, 1, false, stageA(23, 1));
    BARR;
    GPH2(0, 2, false, NOPX);
    GPH2(0, 3, false, NOPX);
    VM0; BARR;
    GPH2(1, 0, true,  NOPX);
    GPH2(1, 1, false, NOPX);
    GPH2(1, 2, false, NOPX);
    GPH2(1, 3, false, NOPX);
#undef GPH2
#undef BARR
#undef VM4
#undef VM0
#undef NOPX

    // ---- epilogue: gate = sigmoid(acc + gc), pack 4 x u8
    const int rg = g << 2;
    const int b = nt * 4 + wn;               // uniform per wave
    const float* gcrow = gc2 + (size_t)b * VOCP2;
#pragma unroll
    for (int m = 0; m < 8; ++m) {
        int v0 = mt * 256 + wm * 128 + m * 16 + rg;
        float4 gcv = *(const float4*)(gcrow + v0);
#pragma unroll
        for (int ni = 0; ni < 4; ++ni) {
            int n = nt * 256 + wn * 64 + ni * 16 + lrow;
            unsigned pk = 0;
#pragma unroll
            for (int r = 0; r < 4; ++r) {
                float garg = acc[m][ni][r] + ((const float*)&gcv)[r];
                float gate = 1.0f / (1.0f + expf(-garg));
                pk |= ((unsigned)(int)(gate * 255.0f + 0.5f)) << (8 * r);
            }
            *(unsigned*)(g8 + (size_t)n * VOCP2 + v0) = pk;
        }
    }
}

// ------------------------------------------------- FUSED persistent GRU + helper blocks
// Blocks 0..63: GRU v5 (r15-validated, byte-identical). Blocks 64..255: helpers —
// sk32 gc/ks tasks (identical math to validated k_sk32) then ILP-x4 cvt/pad copies.
__global__ __launch_bounds__(256, 1) void k_gru_f(const u16* __restrict__ WhhB,
                                                  const float* __restrict__ GI,
                                                  const float* __restrict__ bhh,
                                                  const u16* __restrict__ h0b,
                                                  u16* __restrict__ BG,
                                                  unsigned* __restrict__ flags,
                                                  const float* __restrict__ embed,
                                                  const float* __restrict__ W3,
                                                  const float* __restrict__ W4,
                                                  const float* __restrict__ dw,
                                                  const float* __restrict__ ew,
                                                  const float* __restrict__ W1,
                                                  const float* __restrict__ W2,
                                                  const float* __restrict__ kvw,
                                                  const u16* __restrict__ Bsk,
                                                  float* __restrict__ gc,
                                                  float* __restrict__ ksb,
                                                  u16* __restrict__ Aemb,
                                                  u16* __restrict__ A34,
                                                  u16* __restrict__ Adwew) {
    __shared__ __align__(16) char smem[163840];
    const int tid = threadIdx.x;

    if (blockIdx.x >= 64) {
        // ---------------- helper path ----------------
        const int hb = blockIdx.x - 64;               // 0..191
        // sk32 tasks: gc (392 tasks of 128 rows), ks (69 tasks)
        for (int t = hb; t < 392; t += 192) sk32_task<0>(t, tid, W1, W2, Bsk, gc);
        for (int t = hb; t < 69; t += 192) sk32_task<1>(t, tid, kvw, nullptr, Bsk, ksb);
        // ILP-x4 cvt copies (64B per thread-iteration)
        const long gtid = (long)hb * 256 + tid;
        const long gstr = 192L * 256;
        // embed -> Aemb (VOC x 32 chunks64)
        for (long i = gtid; i < (long)VOC * 32; i += gstr) {
            int row = (int)(i >> 5), c = ((int)i & 31) * 16;
            cvt64(embed + (size_t)row * 512 + c, Aemb + (size_t)row * 512 + c);
        }
        // W3 -> A34[:, :1024] (VOC x 64 chunks64)
        for (long i = gtid; i < (long)VOC * 64; i += gstr) {
            int row = (int)(i >> 6), c = ((int)i & 63) * 16;
            cvt64(W3 + (size_t)row * 1024 + c, A34 + (size_t)row * 1536 + c);
        }
        // W4 -> A34[:, 1024:1536] (VOC x 32 chunks64)
        for (long i = gtid; i < (long)VOC * 32; i += gstr) {
            int row = (int)(i >> 5), c = ((int)i & 31) * 16;
            cvt64(W4 + (size_t)row * 512 + c, A34 + (size_t)row * 1536 + 1024 + c);
        }
        // dw -> Adwew[:, :1024] (1024 x 64 chunks64)
        for (long i = gtid; i < 1024L * 64; i += gstr) {
            int row = (int)(i >> 6), c = ((int)i & 63) * 16;
            cvt64(dw + (size_t)row * 1024 + c, Adwew + (size_t)row * 1536 + c);
        }
        // ew -> Adwew[:, 1024:1536] (1024 x 32 chunks64)
        for (long i = gtid; i < 1024L * 32; i += gstr) {
            int row = (int)(i >> 5), c = ((int)i & 31) * 16;
            cvt64(ew + (size_t)row * 512 + c, Adwew + (size_t)row * 1536 + 1024 + c);
        }
        // pad A34 rows VOC..VOCP2-1 (u32 zeros)
        for (long i = gtid; i < (long)(VOCP2 - VOC) * 768; i += gstr) {
            int row = VOC + (int)(i / 768), c = (int)(i % 768);
            ((unsigned*)(A34 + (size_t)row * 1536))[c] = 0;
        }
        // pad Aemb rows VOC..VOCP-1
        for (long i = gtid; i < (long)(VOCP - VOC) * 256; i += gstr) {
            int row = VOC + (int)(i >> 8), c = (int)i & 255;
            ((unsigned*)(Aemb + (size_t)row * 512))[c] = 0;
        }
        return;
    }

    // ---------------- GRU path (blocks 0..63), r15-validated ----------------
    const int lane = tid & 63;
    const int w = tid >> 6;
    const int jb = blockIdx.x;            // 0..63
    const int j0 = jb * 16;
    const int jl = tid & 15, bp = tid >> 4;
    const int je = j0 + jl;
    const float bh0 = bhh[je], bh1 = bhh[1024 + je], bh2 = bhh[2048 + je];
    char* Bbase = smem + 98304 + w * 16384;

#pragma unroll
    for (int it = 0; it < 24; ++it) {
        int flat = (it * 4 + w) * 64 + lane;
        int r = flat >> 7, s = flat & 127;
        int ss = s ^ (r & 7);
        int gr = (r >> 4) * 1024 + j0 + (r & 15);
        gload_lds16(WhhB + (size_t)gr * 1024 + ss * 8, smem + (size_t)flat * 16);
    }

    float hpv[2];
#pragma unroll
    for (int rb = 0; rb < 2; ++rb)
        hpv[rb] = bf2f(h0b[(size_t)(bp * 2 + rb) * 1024 + je]);

    const int lrow = lane & 15;
    const int ksel = lane >> 4;

    for (int t = 0; t < 64; ++t) {
        const u16* hsrc = (t == 0) ? h0b : BG + (size_t)(t - 1) * 1536;
        const size_t hstr = (t == 0) ? 1024 : (size_t)64 * 1536;

        // stage ALL 4 chunks of this wave's h K-range (16 gload_lds)
#pragma unroll
        for (int c = 0; c < 4; ++c) {
            char* dst = Bbase + c * 4096;
            int kq0 = w * 256 + c * 64;
#pragma unroll
            for (int q = 0; q < 4; ++q) {
                int flat = q * 64 + lane;
                int r = flat >> 3, s = flat & 7;
                int ss = s ^ (r & 7);
                gload_lds16x<0x11>(hsrc + (size_t)r * hstr + kq0 + ss * 8,
                                   dst + (size_t)flat * 16);
            }
        }
        float gi0[2], gi1[2], gi2[2];
#pragma unroll
        for (int rb = 0; rb < 2; ++rb) {
            const float* gp = GI + ((size_t)((bp * 2 + rb) * 64 + t)) * 3072 + je;
            gi0[rb] = gp[0]; gi1[rb] = gp[1024]; gi2[rb] = gp[2048];
        }
        if (t == 0) {
            __syncthreads();
        } else {
            asm volatile("s_waitcnt vmcnt(0)" ::: "memory");
        }
        __builtin_amdgcn_sched_barrier(0);

        f32x4 acc[3][2];
#pragma unroll
        for (int mi = 0; mi < 3; ++mi)
#pragma unroll
            for (int ni = 0; ni < 2; ++ni) acc[mi][ni] = (f32x4){0.f, 0.f, 0.f, 0.f};

#pragma unroll
        for (int c = 0; c < 4; ++c) {
            char* Bb = Bbase + c * 4096;
#pragma unroll
            for (int ks = 0; ks < 2; ++ks) {
                int kb = ks * 64 + ksel * 16;
                bf16x8 bfr[2];
#pragma unroll
                for (int ni = 0; ni < 2; ++ni) {
                    int br = ni * 16 + lrow;
                    bfr[ni] = *(const bf16x8*)(Bb + br * 128 + (kb ^ ((br & 7) << 4)));
                }
                int kA = w * 512 + c * 128 + kb;
#pragma unroll
                for (int mi = 0; mi < 3; ++mi) {
                    int ar = mi * 16 + lrow;
                    bf16x8 af = *(const bf16x8*)(smem + ar * 2048 + (kA ^ ((ar & 7) << 4)));
#pragma unroll
                    for (int ni = 0; ni < 2; ++ni)
                        acc[mi][ni] = __builtin_amdgcn_mfma_f32_16x16x32_bf16(af, bfr[ni], acc[mi][ni], 0, 0, 0);
                }
            }
        }

        float (*epiw)[33] = (float(*)[33])Bbase;
        asm volatile("s_waitcnt lgkmcnt(0)" ::: "memory");
        __builtin_amdgcn_sched_barrier(0);
        {
            const int rg = (lane >> 4) << 2;
#pragma unroll
            for (int mi = 0; mi < 3; ++mi)
#pragma unroll
                for (int ni = 0; ni < 2; ++ni) {
                    int m0 = mi * 16 + rg;
                    int cb = ni * 16 + lrow;
#pragma unroll
                    for (int r = 0; r < 4; ++r) epiw[m0 + r][cb] = acc[mi][ni][r];
                }
        }
        asm volatile("s_waitcnt lgkmcnt(0)" ::: "memory");
        __builtin_amdgcn_s_barrier();

#pragma unroll
        for (int rb = 0; rb < 2; ++rb) {
            int b = bp * 2 + rb;
            float s0 = 0.f, s1 = 0.f, s2 = 0.f;
#pragma unroll
            for (int ww = 0; ww < 4; ++ww) {
                float (*ep)[33] = (float(*)[33])(smem + 98304 + ww * 16384);
                s0 += ep[jl][b]; s1 += ep[16 + jl][b]; s2 += ep[32 + jl][b];
            }
            float rr = sigmoidf_(gi0[rb] + s0 + bh0);
            float zz = sigmoidf_(gi1[rb] + s1 + bh1);
            float nn = tanhf(gi2[rb] + rr * (s2 + bh2));
            float hnew = (1.0f - zz) * nn + zz * hpv[rb];
            hpv[rb] = hnew;
            store_u16_sc(BG + ((size_t)(b * 64 + t)) * 1536 + je, f2bf(hnew));
        }

        if (t < 63) {
            asm volatile("s_waitcnt vmcnt(0)" ::: "memory");
            __syncthreads();
            if (tid == 0)
                __hip_atomic_store(&flags[jb], (unsigned)(t + 1),
                                   __ATOMIC_RELAXED, __HIP_MEMORY_SCOPE_AGENT);
            unsigned tgt = (unsigned)(t + 1);
            while (true) {
                unsigned v = __hip_atomic_load(&flags[lane],
                                               __ATOMIC_RELAXED, __HIP_MEMORY_SCOPE_AGENT);
                if (__all(v >= tgt)) break;
                __builtin_amdgcn_s_sleep(1);
            }
            __builtin_amdgcn_sched_barrier(0);
        }
    }
}

// ------------------------------------------------- per-row lse from partials (NTM tiles)
__global__ __launch_bounds__(256) void k_lse(const float* __restrict__ pmax,
                                             const float* __restrict__ psum,
                                             float* __restrict__ lse) {
    int n = blockIdx.x;
    int t = threadIdx.x;
    __shared__ float sm[256];
    const float* pm = pmax + (size_t)n * NTMP;
    const float* ps = psum + (size_t)n * NTMP;
    float m = -1e30f;
    for (int p = t; p < NTM; p += 256) m = fmaxf(m, pm[p]);
    sm[t] = m;
    __syncthreads();
    for (int s = 128; s > 0; s >>= 1) { if (t < s) sm[t] = fmaxf(sm[t], sm[t + s]); __syncthreads(); }
    m = sm[0];
    __syncthreads();
    float s = 0.0f;
    for (int p = t; p < NTM; p += 256) s += ps[p] * expf(pm[p] - m);
    sm[t] = s;
    __syncthreads();
    for (int r = 128; r > 0; r >>= 1) { if (t < r) sm[t] += sm[t + r]; __syncthreads(); }
    if (t == 0) lse[n] = m + logf(sm[0]);
}

// ------------------------------------------------- final combine (fully coalesced)
__global__ __launch_bounds__(256) void k_final(const u16* __restrict__ Lb,
                                               const unsigned char* __restrict__ g8,
                                               const float* __restrict__ lse,
                                               const float* __restrict__ ks,
                                               const float* __restrict__ lsek,
                                               float* __restrict__ out) {
    int n = blockIdx.y;
    int b = n >> 6;
    float lsen = lse[n], lkb = lsek[b];
    int base = blockIdx.x * 2048;
#pragma unroll
    for (int i = 0; i < 8; ++i) {
        int v = base + i * 256 + threadIdx.x;
        if (v < VOC) {
            float L = bf2f(Lb[(size_t)n * VOCP + v]);
            float g = g8[(size_t)n * VOCP2 + v] * (1.0f / 255.0f);
            float kp = ((v >= 10 && v < 10 + KSN) ? ks[(size_t)b * KSN + (v - 10)] : 0.0f) - lkb;
            out[(size_t)n * VOC + v] = g * (L - lsen) + (1.0f - g) * kp;
        }
    }
}

// ---------------------------------------------------------------- launch
extern "C" void kernel_launch(void* const* d_in, const int* in_sizes, int n_in,
                              void* d_out, int out_size, void* d_ws, size_t ws_size,
                              hipStream_t stream) {
    const float* ses    = (const float*)d_in[0];
    const float* know   = (const float*)d_in[1];
    const int*   target = (const int*)d_in[2];
    const float* embed  = (const float*)d_in[3];
    const float* Wih    = (const float*)d_in[4];
    const float* Whh    = (const float*)d_in[5];
    const float* bih    = (const float*)d_in[6];
    const float* bhh    = (const float*)d_in[7];
    const float* sdw    = (const float*)d_in[8];
    const float* sdb    = (const float*)d_in[9];
    const float* dw     = (const float*)d_in[10];
    const float* siw    = (const float*)d_in[11];
    const float* ew     = (const float*)d_in[12];
    const float* eb     = (const float*)d_in[13];
    const float* W1     = (const float*)d_in[14];
    const float* W2     = (const float*)d_in[15];
    const float* W3     = (const float*)d_in[16];
    const float* W4     = (const float*)d_in[17];
    const float* kvw    = (const float*)d_in[18];

    char* ws = (char*)d_ws;
    size_t o = 0;
    auto alloc = [&](size_t bytes) { char* r = ws + o; o += (bytes + 255) & ~(size_t)255; return r; };
    u16*   Aemb  = (u16*)  alloc((size_t)VOCP * 512 * 2);
    u16*   A34   = (u16*)  alloc((size_t)VOCP2 * 1536 * 2);
    u16*   Adwew = (u16*)  alloc((size_t)1024 * 1536 * 2);
    u16*   Wihb  = (u16*)  alloc((size_t)3072 * 512 * 2);
    u16*   WhhB  = (u16*)  alloc((size_t)3072 * 1024 * 2);
    u16*   h0b   = (u16*)  alloc((size_t)32 * 1024 * 2);
    u16*   BG    = (u16*)  alloc((size_t)2048 * 1536 * 2);
    u16*   BL    = (u16*)  alloc((size_t)2048 * 512 * 2);
    float* GI    = (float*)alloc((size_t)2048 * 3072 * 4);
    float* h0    = (float*)alloc((size_t)32 * 1024 * 4);
    float* sesinf= (float*)alloc((size_t)32 * 1024 * 4);
    float* gc    = (float*)alloc((size_t)32 * VOCP2 * 4);
    float* ksb   = (float*)alloc((size_t)32 * KSN * 4);
    float* lsek  = (float*)alloc(256);
    float* lse   = (float*)alloc((size_t)2048 * 4);
    unsigned* flags = (unsigned*)alloc(256);
    float* pmax  = (float*)alloc((size_t)2048 * NTMP * 4);
    float* psum  = (float*)alloc((size_t)2048 * NTMP * 4);
    unsigned char* g8 = (unsigned char*)alloc((size_t)2048 * VOCP2);
    u16*   Lb    = (u16*)  alloc((size_t)2048 * VOCP * 2);
    u16*   Bsk   = (u16*)  alloc((size_t)128 * 2048 * 2);
    float* out = (float*)d_out;

    hipMemsetAsync(flags, 0, 256, stream);

    // small preparations (big cvts + gc/ks GEMMs folded into k_gru_f helpers)
    k_cvt<<<dim3(3072, 1), 256, 0, stream>>>(Wih, Wihb, 512, 512, 512);
    k_cvt<<<dim3(3072, 1), 256, 0, stream>>>(Whh, WhhB, 1024, 1024, 1024);
    k_bsk<<<dim3(128), 256, 0, stream>>>(ses, know, Bsk);
    k_gather<<<dim3(2048), 128, 0, stream>>>(embed, target, BG);
    k_h0_sesinf<<<dim3(32), 256, 0, stream>>>(ses, sdw, sdb, siw, h0, sesinf);
    k_cvt<<<dim3(32, 1), 256, 0, stream>>>(h0, h0b, 1024, 1024, 1024);

    // GI = TE @ Wih.T + bih
    gemm_bt<0><<<dim3(16, 24), 256, 0, stream>>>(Wihb, 512, BG + 1024, 1536, 512,
                                                 bih, nullptr, GI, nullptr, nullptr);
    // FUSED: GRU (blocks 0..63) + helpers (gc/ks GEMMs, weight cvts, pads)
    k_gru_f<<<dim3(256), 256, 0, stream>>>(WhhB, GI, bhh, h0b, BG, flags,
                                           embed, W3, W4, dw, ew,
                                           W1, W2, kvw, Bsk, gc, ksb,
                                           Aemb, A34, Adwew);
    k_lseknow<<<dim3(32), 256, 0, stream>>>(ksb, lsek);
    // MX (maxout) -> BL
    gemm_bt<1><<<dim3(16, 8), 256, 0, stream>>>(Adwew, 1536, BG, 1536, 1536,
                                                sesinf, eb, nullptr, BL, nullptr);
    // gate GEMM -> g8  (256-tile, minimal-barrier 8-phase, sound ledger)
    gemm_gate8<<<dim3(1568), 512, 0, stream>>>(A34, BG, gc, g8);
    // logit GEMM -> Lb + partials (128-tile, Lb stride VOCP)
    gemm_bt<3><<<dim3(16, NTM), 256, 0, stream>>>(Aemb, 512, BL, 512, 512,
                                                  nullptr, nullptr, pmax, Lb, psum);
    k_lse<<<dim3(2048), 256, 0, stream>>>(pmax, psum, lse);
    k_final<<<dim3(25, 2048), 256, 0, stream>>>(Lb, g8, lse, ksb, lsek, out);
}